// Round 9
// baseline (397.202 us; speedup 1.0000x reference)
//
#include <hip/hip_runtime.h>
#include <hip/hip_bf16.h>

// ---------------------------------------------------------------------------
// GCN: h = relu(GCNConv(x,W1,b1)); x1 = relu(GCNConv(h,W2,b2));
//      x2 = meanpool(x1,batch); out = log_softmax(relu(x2@fc1+b)@fc2+b)
//
// R9: gather restructured wave-per-node: bucket register-prefetch (one
// coalesced 256B burst) + __shfl broadcast in the edge loop -- removes the
// bucket->table dependent load chain and 4x-redundant slot reads that left
// R8's gather latency-bound (52% VALU / 66% occ / neither pipe saturated).
// 16 edges in flight per wave. CSR pipeline / bf16 sliced tables unchanged.
// ---------------------------------------------------------------------------

#define CAP 64
#define OVFCAP 8192
#define MAXNR 6400   // max nodes per range (LDS histogram)
#define PCH 32       // chunks per range in the place pipeline

__device__ inline unsigned short f2bf(float f) {   // fp32 -> bf16 RNE
    unsigned u = __float_as_uint(f);
    u += 0x7FFFu + ((u >> 16) & 1u);
    return (unsigned short)(u >> 16);
}

// P1: partition edges into 8 per-range lists rng[r] of (col, row<<15|q15(ew)).
__global__ void part_kernel(const int* __restrict__ rows, const int* __restrict__ cols,
                            const float* __restrict__ ew, int* __restrict__ rangeCnt,
                            uint2* __restrict__ rng, int E, int NR, int RSEG) {
    __shared__ int hc[8];
    const int t = threadIdx.x;
    const int nb = gridDim.x;
    const int CS = (E + nb - 1) / nb;
    const int e0 = blockIdx.x * CS, e1 = min(e0 + CS, E);
    if (t < 8) hc[t] = 0;
    __syncthreads();
    for (int e = e0 + t; e < e1; e += 256) {
        int r = cols[e] / NR;
        atomicAdd(&hc[r], 1);
    }
    __syncthreads();
    if (t < 8) hc[t] = atomicAdd(&rangeCnt[t], hc[t]);   // hc becomes cursor base
    __syncthreads();
    for (int e = e0 + t; e < e1; e += 256) {
        int c = cols[e];
        int r = c / NR;
        int q = (int)(ew[e] * 32768.0f);
        if (q > 32767) q = 32767;
        unsigned rec = ((unsigned)rows[e] << 15) | (unsigned)q;
        int pos = atomicAdd(&hc[r], 1);
        if (pos < RSEG) rng[(size_t)r * RSEG + pos] = make_uint2((unsigned)c, rec);
    }
}

// P2a: per-(range,chunk) LDS histogram -> h2d[(r*PCH+j)*NR + c]
__global__ __launch_bounds__(1024)
void hist2_kernel(const uint2* __restrict__ rng, const int* __restrict__ rangeCnt,
                  int* __restrict__ h2d, int NR, int RSEG) {
    __shared__ int hist[MAXNR];
    const int r = blockIdx.x & 7, j = blockIdx.x >> 3;
    const int t = threadIdx.x;
    const int M = min(rangeCnt[r], RSEG);
    const int CS = (M + PCH - 1) / PCH;
    const int e0 = j * CS, e1 = min(e0 + CS, M);
    for (int n = t; n < NR; n += 1024) hist[n] = 0;
    __syncthreads();
    const uint2* lst = rng + (size_t)r * RSEG;
    for (int k = e0 + t; k < e1; k += 1024)
        atomicAdd(&hist[lst[k].x - r * NR], 1);
    __syncthreads();
    int* dst = h2d + (size_t)(r * PCH + j) * NR;
    for (int n = t; n < NR; n += 1024) dst[n] = hist[n];
}

// P2b: per-node exclusive prefix over the PCH chunk counts -> bases in-place,
// total -> cnt[n].  Zero atomics, deterministic.  (Reads are coalesced: threads
// n..n+63 read consecutive ints for each fixed j.)
__global__ void scan2_kernel(int* __restrict__ h2d, int* __restrict__ cnt, int NR, int N) {
    int n = blockIdx.x * 256 + threadIdx.x;
    if (n >= N) return;
    int r = n / NR, c = n - r * NR;
    int* col = h2d + (size_t)(r * PCH) * NR + c;
    int run = 0;
    #pragma unroll 8
    for (int j = 0; j < PCH; ++j) {
        int v = col[(size_t)j * NR];
        col[(size_t)j * NR] = run;
        run += v;
    }
    cnt[n] = run;
}

// P2c: write slot records at deterministic positions (chunk base + LDS cursor).
__global__ __launch_bounds__(1024)
void place2_kernel(const uint2* __restrict__ rng, const int* __restrict__ rangeCnt,
                   const int* __restrict__ h2d, unsigned* __restrict__ slot,
                   int4* __restrict__ ovf, int* __restrict__ ovfcnt,
                   int NR, int RSEG) {
    __shared__ int cur[MAXNR];
    const int r = blockIdx.x & 7, j = blockIdx.x >> 3;
    const int t = threadIdx.x;
    const int M = min(rangeCnt[r], RSEG);
    const int CS = (M + PCH - 1) / PCH;
    const int e0 = j * CS, e1 = min(e0 + CS, M);
    const int* src = h2d + (size_t)(r * PCH + j) * NR;
    for (int n = t; n < NR; n += 1024) cur[n] = src[n];
    __syncthreads();
    const uint2* lst = rng + (size_t)r * RSEG;
    for (int k = e0 + t; k < e1; k += 1024) {
        uint2 u2 = lst[k];
        int pos = atomicAdd(&cur[u2.x - r * NR], 1);   // LDS cursor
        if (pos < CAP) {
            slot[(size_t)u2.x * CAP + pos] = u2.y;
        } else {
            int o = atomicAdd(ovfcnt, 1);
            if (o < OVFCAP)
                ovf[o] = make_int4((int)(u2.y >> 15), (int)u2.x, (int)(u2.y & 32767u), 0);
        }
    }
}

// Fallback for N too large for LDS histogram (not taken here).
__global__ void place_simple_kernel(const int* __restrict__ rows, const int* __restrict__ cols,
                                    const float* __restrict__ ew, int* __restrict__ cnt,
                                    unsigned* __restrict__ slot, int4* __restrict__ ovf,
                                    int* __restrict__ ovfcnt, int E) {
    int e = blockIdx.x * 256 + threadIdx.x;
    if (e >= E) return;
    int r = rows[e], c = cols[e];
    int q = (int)(ew[e] * 32768.0f);
    if (q > 32767) q = 32767;
    int pos = atomicAdd(&cnt[c], 1);
    if (pos < CAP) {
        slot[(size_t)c * CAP + pos] = ((unsigned)r << 15) | (unsigned)q;
    } else {
        int o = atomicAdd(ovfcnt, 1);
        if (o < OVFCAP) ovf[o] = make_int4(r, c, q, 0);
    }
}

// dinv[i] = rsqrt(sum of bucket weights (+ ovf entries if cnt>CAP) + 1).
__global__ void degfin_kernel(const unsigned* __restrict__ slot, const int* __restrict__ cnt,
                              const int4* __restrict__ ovf, const int* __restrict__ ovfcnt,
                              float* __restrict__ dinv, int N) {
    const int w = threadIdx.x >> 6, lane = threadIdx.x & 63;
    const int i = blockIdx.x * 4 + w;
    if (i >= N) return;
    int mraw = cnt[i];
    int m = mraw > CAP ? CAP : mraw;
    float v = 0.f;
    if (lane < m) v = (float)(slot[(size_t)i * CAP + lane] & 32767u);
    if (mraw > CAP) {
        int oc = *ovfcnt; if (oc > OVFCAP) oc = OVFCAP;
        for (int k = lane; k < oc; k += 64)
            if (ovf[k].y == i) v += (float)ovf[k].z;
    }
    #pragma unroll
    for (int off = 1; off < 64; off <<= 1) v += __shfl_xor(v, off);
    if (lane == 0) dinv[i] = rsqrtf(v * (1.0f / 32768.0f) + 1.0f);
}

// outbf[slice][M][32] (bf16) = (A[M][128] @ W[128][BN]) * dinv[row] * 2^-15.
template <int BN, int S>
__global__ void gemm_kernel(const float* __restrict__ A, const float* __restrict__ W,
                            const float* __restrict__ dinv, unsigned short* __restrict__ outbf,
                            int M) {
    constexpr int K = 128;
    constexpr int BK = 32;
    constexpr int CG = BN / 4;
    constexpr int RG = 256 / CG;
    constexpr int BM = RG * 4;
    __shared__ float xs[BM][BK + 4];
    __shared__ float ws[BK][BN];
    const int t = threadIdx.x;
    const int cg = t % CG, rg = t / CG;
    const int c0 = cg * 4, r0 = rg * 4;
    const int rowBase = blockIdx.x * BM;
    float acc[4][4] = {};
    for (int k0 = 0; k0 < K; k0 += BK) {
        constexpr int XL = BM * BK / (256 * 4);
        #pragma unroll
        for (int i = 0; i < XL; ++i) {
            int f = (t + i * 256) * 4;
            int rr = f / BK, kk = f % BK;
            int grow = rowBase + rr;
            float4 v = (grow < M) ? *(const float4*)&A[(size_t)grow * K + k0 + kk]
                                  : make_float4(0.f, 0.f, 0.f, 0.f);
            *(float4*)&xs[rr][kk] = v;
        }
        constexpr int WL = BK * BN / (256 * 4);
        #pragma unroll
        for (int i = 0; i < WL; ++i) {
            int f = (t + i * 256) * 4;
            int kk = f / BN, cc = f % BN;
            *(float4*)&ws[kk][cc] = *(const float4*)&W[(size_t)(k0 + kk) * BN + cc];
        }
        __syncthreads();
        #pragma unroll
        for (int kk = 0; kk < BK; ++kk) {
            float4 wv = *(float4*)&ws[kk][c0];
            float xv[4];
            #pragma unroll
            for (int i = 0; i < 4; ++i) xv[i] = xs[r0 + i][kk];
            #pragma unroll
            for (int i = 0; i < 4; ++i) {
                acc[i][0] += xv[i] * wv.x;
                acc[i][1] += xv[i] * wv.y;
                acc[i][2] += xv[i] * wv.z;
                acc[i][3] += xv[i] * wv.w;
            }
        }
        __syncthreads();
    }
    const int slice = c0 >> 5, cw = c0 & 31;
    #pragma unroll
    for (int i = 0; i < 4; ++i) {
        int grow = rowBase + r0 + i;
        if (grow < M) {
            float s = dinv[grow] * (1.0f / 32768.0f);
            unsigned p0 = (unsigned)f2bf(acc[i][0] * s) | ((unsigned)f2bf(acc[i][1] * s) << 16);
            unsigned p1 = (unsigned)f2bf(acc[i][2] * s) | ((unsigned)f2bf(acc[i][3] * s) << 16);
            *(uint2*)&outbf[((size_t)slice * M + grow) * 32 + cw] = make_uint2(p0, p1);
        }
    }
}

// Wave-per-node sliced bf16 aggregation. slice = blockIdx%S -> XCD-local
// 3.2MB sub-table [N][32 bf16]. Lane = e*4+cg: 16 edges in flight x 4 lanes
// (uint4 = 8 bf16). Bucket prefetched into registers (one coalesced 256B
// burst), edge loop reads records via __shfl -- no in-loop bucket memory
// traffic, no load->load chain. Invalid slots carry rec=0 (coef 0, row 0).
// Epilogue: relu(d*acc + self*(d*32768) + b) in fp32.
template <int F, int S>
__global__ void gather_kernel(const unsigned short* __restrict__ xsb,
                              const unsigned* __restrict__ slot,
                              const int* __restrict__ cnt, const float* __restrict__ dinv,
                              const float* __restrict__ b, const int4* __restrict__ ovf,
                              const int* __restrict__ ovfcnt, float* __restrict__ out, int N) {
    const int slice = blockIdx.x % S;
    const int grp = blockIdx.x / S;
    const int w = threadIdx.x >> 6, lane = threadIdx.x & 63;
    const int cg = lane & 3;
    const int e  = lane >> 2;        // 0..15
    const int i = grp * 4 + w;
    const bool iv = (i < N);
    const int ic = iv ? i : 0;
    const uint4* xs4 = (const uint4*)(xsb + (size_t)slice * N * 32);
    int mraw = iv ? cnt[ic] : 0;
    int m = mraw > CAP ? CAP : mraw;
    const unsigned* bkt = slot + (size_t)ic * CAP;
    unsigned rec = 0;
    if (lane < m) rec = bkt[lane];   // coalesced bucket prefetch
    float acc[8] = {};
    for (int j0 = 0; j0 < m; j0 += 16) {
        unsigned u = __shfl(rec, j0 + e);
        float c = (float)(u & 32767u);
        uint4 a = xs4[(size_t)(u >> 15) * 4 + cg];
        acc[0] += __uint_as_float(a.x << 16) * c;
        acc[1] += __uint_as_float(a.x & 0xFFFF0000u) * c;
        acc[2] += __uint_as_float(a.y << 16) * c;
        acc[3] += __uint_as_float(a.y & 0xFFFF0000u) * c;
        acc[4] += __uint_as_float(a.z << 16) * c;
        acc[5] += __uint_as_float(a.z & 0xFFFF0000u) * c;
        acc[6] += __uint_as_float(a.w << 16) * c;
        acc[7] += __uint_as_float(a.w & 0xFFFF0000u) * c;
    }
    if (mraw > CAP) {                     // inline overflow (normally skipped)
        int oc = *ovfcnt; if (oc > OVFCAP) oc = OVFCAP;
        for (int k = e; k < oc; k += 16) {
            int4 r4 = ovf[k];
            if (r4.y == i) {
                float c = (float)r4.z;
                uint4 a = xs4[(size_t)r4.x * 4 + cg];
                acc[0] += __uint_as_float(a.x << 16) * c;
                acc[1] += __uint_as_float(a.x & 0xFFFF0000u) * c;
                acc[2] += __uint_as_float(a.y << 16) * c;
                acc[3] += __uint_as_float(a.y & 0xFFFF0000u) * c;
                acc[4] += __uint_as_float(a.z << 16) * c;
                acc[5] += __uint_as_float(a.z & 0xFFFF0000u) * c;
                acc[6] += __uint_as_float(a.w << 16) * c;
                acc[7] += __uint_as_float(a.w & 0xFFFF0000u) * c;
            }
        }
    }
    #pragma unroll
    for (int k = 0; k < 8; ++k) {
        acc[k] += __shfl_xor(acc[k], 4);
        acc[k] += __shfl_xor(acc[k], 8);
        acc[k] += __shfl_xor(acc[k], 16);
        acc[k] += __shfl_xor(acc[k], 32);
    }
    if (e == 0 && iv) {
        float d = dinv[i];
        float sd = d * 32768.0f;
        uint4 sv = xs4[(size_t)i * 4 + cg];
        float s0 = __uint_as_float(sv.x << 16), s1 = __uint_as_float(sv.x & 0xFFFF0000u);
        float s2 = __uint_as_float(sv.y << 16), s3 = __uint_as_float(sv.y & 0xFFFF0000u);
        float s4 = __uint_as_float(sv.z << 16), s5 = __uint_as_float(sv.z & 0xFFFF0000u);
        float s6 = __uint_as_float(sv.w << 16), s7 = __uint_as_float(sv.w & 0xFFFF0000u);
        const float* bb = &b[slice * 32 + cg * 8];
        float4 bb0 = *(const float4*)&bb[0];
        float4 bb1 = *(const float4*)&bb[4];
        float4 o0, o1;
        o0.x = fmaxf(acc[0] * d + s0 * sd + bb0.x, 0.f);
        o0.y = fmaxf(acc[1] * d + s1 * sd + bb0.y, 0.f);
        o0.z = fmaxf(acc[2] * d + s2 * sd + bb0.z, 0.f);
        o0.w = fmaxf(acc[3] * d + s3 * sd + bb0.w, 0.f);
        o1.x = fmaxf(acc[4] * d + s4 * sd + bb1.x, 0.f);
        o1.y = fmaxf(acc[5] * d + s5 * sd + bb1.y, 0.f);
        o1.z = fmaxf(acc[6] * d + s6 * sd + bb1.z, 0.f);
        o1.w = fmaxf(acc[7] * d + s7 * sd + bb1.w, 0.f);
        float* dst = &out[(size_t)i * F + slice * 32 + cg * 8];
        *(float4*)&dst[0] = o0;
        *(float4*)&dst[4] = o1;
    }
}

// sums[batch[n]] += x1[n]; cnt[batch[n]] += 1 (sorted batch, boundary atomics)
__global__ void pool_kernel(const float* __restrict__ x1, const int* __restrict__ batch,
                            float* __restrict__ sums, float* __restrict__ cnt, int N) {
    constexpr int QG = 16, S = 16, ITER = 16;
    int t = threadIdx.x;
    int q = t % QG, s = t / QG;
    int n0 = blockIdx.x * (S * ITER) + s * ITER;
    float4 acc = make_float4(0.f, 0.f, 0.f, 0.f);
    float cacc = 0.f;
    int gcur = -1;
    for (int i = 0; i < ITER; ++i) {
        int n = n0 + i;
        if (n >= N) break;
        int gid = batch[n];
        if (gid != gcur) {
            if (gcur >= 0) {
                float* dst = &sums[gcur * 64 + q * 4];
                atomicAdd(dst + 0, acc.x);
                atomicAdd(dst + 1, acc.y);
                atomicAdd(dst + 2, acc.z);
                atomicAdd(dst + 3, acc.w);
                if (q == 0) atomicAdd(&cnt[gcur], cacc);
            }
            gcur = gid;
            acc = make_float4(0.f, 0.f, 0.f, 0.f);
            cacc = 0.f;
        }
        float4 a = ((const float4*)x1)[n * QG + q];
        acc.x += a.x; acc.y += a.y; acc.z += a.z; acc.w += a.w;
        if (q == 0) cacc += 1.f;
    }
    if (gcur >= 0) {
        float* dst = &sums[gcur * 64 + q * 4];
        atomicAdd(dst + 0, acc.x);
        atomicAdd(dst + 1, acc.y);
        atomicAdd(dst + 2, acc.z);
        atomicAdd(dst + 3, acc.w);
        if (q == 0) atomicAdd(&cnt[gcur], cacc);
    }
}

// Final MLP head + log_softmax, one block. G=64 graphs.
__global__ void head_kernel(const float* __restrict__ sums, const float* __restrict__ cnt,
                            const float* __restrict__ fc1W, const float* __restrict__ fc1b,
                            const float* __restrict__ fc2W, const float* __restrict__ fc2b,
                            float* __restrict__ out) {
    __shared__ float x2[64 * 64];
    __shared__ float h[64 * 128];
    __shared__ float logits[64 * 2];
    int t = threadIdx.x;
    for (int i = t; i < 64 * 64; i += 256) {
        int g = i / 64;
        x2[i] = sums[i] / fmaxf(cnt[g], 1.f);
    }
    __syncthreads();
    for (int i = t; i < 64 * 128; i += 256) {
        int g = i / 128, k = i % 128;
        float a = fc1b[k];
        #pragma unroll 8
        for (int j = 0; j < 64; ++j) a += x2[g * 64 + j] * fc1W[j * 128 + k];
        h[i] = fmaxf(a, 0.f);
    }
    __syncthreads();
    if (t < 128) {
        int g = t / 2, m = t % 2;
        float a = fc2b[m];
        #pragma unroll 8
        for (int k = 0; k < 128; ++k) a += h[g * 128 + k] * fc2W[k * 2 + m];
        logits[t] = a;
    }
    __syncthreads();
    if (t < 128) {
        int g = t / 2, m = t % 2;
        float l0 = logits[g * 2 + 0], l1 = logits[g * 2 + 1];
        float mx = fmaxf(l0, l1);
        float lse = mx + logf(expf(l0 - mx) + expf(l1 - mx));
        out[t] = (m == 0 ? l0 : l1) - lse;
    }
}

extern "C" void kernel_launch(void* const* d_in, const int* in_sizes, int n_in,
                              void* d_out, int out_size, void* d_ws, size_t ws_size,
                              hipStream_t stream) {
    const float* x      = (const float*)d_in[0];
    const int*   eidx   = (const int*)d_in[1];
    const float* ew     = (const float*)d_in[2];
    const int*   batch  = (const int*)d_in[3];
    const float* W1     = (const float*)d_in[4];
    const float* b1     = (const float*)d_in[5];
    const float* W2     = (const float*)d_in[6];
    const float* b2     = (const float*)d_in[7];
    const float* fc1W   = (const float*)d_in[8];
    const float* fc1b   = (const float*)d_in[9];
    const float* fc2W   = (const float*)d_in[10];
    const float* fc2b   = (const float*)d_in[11];
    float* out = (float*)d_out;

    const int N = in_sizes[3];          // 50000 nodes
    const int E = in_sizes[2];          // 1600000 edges
    const int* rows = eidx;
    const int* cols = eidx + E;
    const int NR = (N + 7) / 8;
    const int RSEG = E / 8 + 32768;

    float* ws = (float*)d_ws;
    size_t off = 0;
    auto alloc = [&](size_t n) { float* p = ws + off; off += (n + 15) & ~(size_t)15; return p; };
    // --- zero-initialized region ---
    float*    sums     = alloc(64 * 64);
    float*    cntf     = alloc(16);
    int*      ovfcnt   = (int*)alloc(16);
    int*      rangeCnt = (int*)alloc(16);
    int*      cnt      = (int*)alloc(N);          // zeroed for fallback path only
    size_t zfloats = off;
    // --- rest ---
    float*    dinv   = alloc(N);
    unsigned* slot   = (unsigned*)alloc((size_t)N * CAP);
    int4*     ovf    = (int4*)alloc((size_t)OVFCAP * 4);
    float*    bufA   = alloc((size_t)N * 128);   // h2d | xw1bf | xw2bf + x1
    float*    bufB   = alloc((size_t)N * 128);   // rng | h
    int*            h2d   = (int*)bufA;                       // 8*PCH*NR ints, dead before xw1bf
    unsigned short* xw1bf = (unsigned short*)bufA;            // [4][N][32] bf16
    unsigned short* xw2bf = (unsigned short*)bufA;            // [2][N][32] bf16
    float*          x1    = bufA + (size_t)N * 32;            // after xw2bf (N*64 ushorts)
    uint2*          rng   = (uint2*)bufB;                     // 8*RSEG uint2, dead before h
    float*          h     = bufB;
    (void)ws_size;

    hipMemsetAsync(d_ws, 0, zfloats * sizeof(float), stream);

    // CSR build: partition -> histogram -> prefix -> place (no contended atomics)
    if (NR <= MAXNR) {
        part_kernel<<<256, 256, 0, stream>>>(rows, cols, ew, rangeCnt, rng, E, NR, RSEG);
        hist2_kernel<<<8 * PCH, 1024, 0, stream>>>(rng, rangeCnt, h2d, NR, RSEG);
        scan2_kernel<<<(N + 255) / 256, 256, 0, stream>>>(h2d, cnt, NR, N);
        place2_kernel<<<8 * PCH, 1024, 0, stream>>>(rng, rangeCnt, h2d, slot, ovf, ovfcnt, NR, RSEG);
    } else {
        place_simple_kernel<<<(E + 255) / 256, 256, 0, stream>>>(rows, cols, ew, cnt, slot, ovf, ovfcnt, E);
    }
    degfin_kernel<<<(N + 3) / 4, 256, 0, stream>>>(slot, cnt, ovf, ovfcnt, dinv, N);

    // Layer 1: bf16 table, 4 slices of 32 features (3.2MB per XCD-group)
    gemm_kernel<128, 4><<<(N + 31) / 32, 256, 0, stream>>>(x, W1, dinv, xw1bf, N);
    gather_kernel<128, 4><<<((N + 3) / 4) * 4, 256, 0, stream>>>(xw1bf, slot, cnt, dinv, b1, ovf, ovfcnt, h, N);

    // Layer 2: bf16 table, 2 slices of 32 features
    gemm_kernel<64, 2><<<(N + 63) / 64, 256, 0, stream>>>(h, W2, dinv, xw2bf, N);
    gather_kernel<64, 2><<<((N + 3) / 4) * 2, 256, 0, stream>>>(xw2bf, slot, cnt, dinv, b2, ovf, ovfcnt, x1, N);

    // Mean-pool + head
    pool_kernel<<<(N + 255) / 256, 256, 0, stream>>>(x1, batch, sums, cntf, N);
    head_kernel<<<1, 256, 0, stream>>>(sums, cntf, fc1W, fc1b, fc2W, fc2b, out);
}

// Round 10
// 341.826 us; speedup vs baseline: 1.1620x; 1.1620x over previous
//
#include <hip/hip_runtime.h>
#include <hip/hip_bf16.h>

// ---------------------------------------------------------------------------
// GCN: h = relu(GCNConv(x,W1,b1)); x1 = relu(GCNConv(h,W2,b2));
//      x2 = meanpool(x1,batch); out = log_softmax(relu(x2@fc1+b)@fc2+b)
//
// R10: R9's wave-per-node gather regressed (4x waves, 2x reduction depth ->
// VALU-bound 70%). Revert to R8's 4-node/4-edge/4-lane layout, but stage the
// block's 16 buckets into LDS first (coalesced uint4, stride-68 pad ->
// conflict-free): kills the bucket->table dependent chain and the 4x
// redundant slot reads that R8 paid, at R8's wave economy.
// ---------------------------------------------------------------------------

#define CAP 64
#define OVFCAP 8192
#define MAXNR 6400   // max nodes per range (LDS histogram)
#define PCH 32       // chunks per range in the place pipeline
#define BSTR 68      // LDS bucket stride (words): 4nd+e bank spread, 16B aligned

__device__ inline unsigned short f2bf(float f) {   // fp32 -> bf16 RNE
    unsigned u = __float_as_uint(f);
    u += 0x7FFFu + ((u >> 16) & 1u);
    return (unsigned short)(u >> 16);
}

// P1: partition edges into 8 per-range lists rng[r] of (col, row<<15|q15(ew)).
__global__ void part_kernel(const int* __restrict__ rows, const int* __restrict__ cols,
                            const float* __restrict__ ew, int* __restrict__ rangeCnt,
                            uint2* __restrict__ rng, int E, int NR, int RSEG) {
    __shared__ int hc[8];
    const int t = threadIdx.x;
    const int nb = gridDim.x;
    const int CS = (E + nb - 1) / nb;
    const int e0 = blockIdx.x * CS, e1 = min(e0 + CS, E);
    if (t < 8) hc[t] = 0;
    __syncthreads();
    for (int e = e0 + t; e < e1; e += 256) {
        int r = cols[e] / NR;
        atomicAdd(&hc[r], 1);
    }
    __syncthreads();
    if (t < 8) hc[t] = atomicAdd(&rangeCnt[t], hc[t]);   // hc becomes cursor base
    __syncthreads();
    for (int e = e0 + t; e < e1; e += 256) {
        int c = cols[e];
        int r = c / NR;
        int q = (int)(ew[e] * 32768.0f);
        if (q > 32767) q = 32767;
        unsigned rec = ((unsigned)rows[e] << 15) | (unsigned)q;
        int pos = atomicAdd(&hc[r], 1);
        if (pos < RSEG) rng[(size_t)r * RSEG + pos] = make_uint2((unsigned)c, rec);
    }
}

// P2a: per-(range,chunk) LDS histogram -> h2d[(r*PCH+j)*NR + c]
__global__ __launch_bounds__(1024)
void hist2_kernel(const uint2* __restrict__ rng, const int* __restrict__ rangeCnt,
                  int* __restrict__ h2d, int NR, int RSEG) {
    __shared__ int hist[MAXNR];
    const int r = blockIdx.x & 7, j = blockIdx.x >> 3;
    const int t = threadIdx.x;
    const int M = min(rangeCnt[r], RSEG);
    const int CS = (M + PCH - 1) / PCH;
    const int e0 = j * CS, e1 = min(e0 + CS, M);
    for (int n = t; n < NR; n += 1024) hist[n] = 0;
    __syncthreads();
    const uint2* lst = rng + (size_t)r * RSEG;
    for (int k = e0 + t; k < e1; k += 1024)
        atomicAdd(&hist[lst[k].x - r * NR], 1);
    __syncthreads();
    int* dst = h2d + (size_t)(r * PCH + j) * NR;
    for (int n = t; n < NR; n += 1024) dst[n] = hist[n];
}

// P2b: per-node exclusive prefix over the PCH chunk counts -> bases in-place,
// total -> cnt[n].  Zero atomics, deterministic.
__global__ void scan2_kernel(int* __restrict__ h2d, int* __restrict__ cnt, int NR, int N) {
    int n = blockIdx.x * 256 + threadIdx.x;
    if (n >= N) return;
    int r = n / NR, c = n - r * NR;
    int* col = h2d + (size_t)(r * PCH) * NR + c;
    int run = 0;
    #pragma unroll 8
    for (int j = 0; j < PCH; ++j) {
        int v = col[(size_t)j * NR];
        col[(size_t)j * NR] = run;
        run += v;
    }
    cnt[n] = run;
}

// P2c: write slot records at deterministic positions (chunk base + LDS cursor).
__global__ __launch_bounds__(1024)
void place2_kernel(const uint2* __restrict__ rng, const int* __restrict__ rangeCnt,
                   const int* __restrict__ h2d, unsigned* __restrict__ slot,
                   int4* __restrict__ ovf, int* __restrict__ ovfcnt,
                   int NR, int RSEG) {
    __shared__ int cur[MAXNR];
    const int r = blockIdx.x & 7, j = blockIdx.x >> 3;
    const int t = threadIdx.x;
    const int M = min(rangeCnt[r], RSEG);
    const int CS = (M + PCH - 1) / PCH;
    const int e0 = j * CS, e1 = min(e0 + CS, M);
    const int* src = h2d + (size_t)(r * PCH + j) * NR;
    for (int n = t; n < NR; n += 1024) cur[n] = src[n];
    __syncthreads();
    const uint2* lst = rng + (size_t)r * RSEG;
    for (int k = e0 + t; k < e1; k += 1024) {
        uint2 u2 = lst[k];
        int pos = atomicAdd(&cur[u2.x - r * NR], 1);   // LDS cursor
        if (pos < CAP) {
            slot[(size_t)u2.x * CAP + pos] = u2.y;
        } else {
            int o = atomicAdd(ovfcnt, 1);
            if (o < OVFCAP)
                ovf[o] = make_int4((int)(u2.y >> 15), (int)u2.x, (int)(u2.y & 32767u), 0);
        }
    }
}

// Fallback for N too large for LDS histogram (not taken here).
__global__ void place_simple_kernel(const int* __restrict__ rows, const int* __restrict__ cols,
                                    const float* __restrict__ ew, int* __restrict__ cnt,
                                    unsigned* __restrict__ slot, int4* __restrict__ ovf,
                                    int* __restrict__ ovfcnt, int E) {
    int e = blockIdx.x * 256 + threadIdx.x;
    if (e >= E) return;
    int r = rows[e], c = cols[e];
    int q = (int)(ew[e] * 32768.0f);
    if (q > 32767) q = 32767;
    int pos = atomicAdd(&cnt[c], 1);
    if (pos < CAP) {
        slot[(size_t)c * CAP + pos] = ((unsigned)r << 15) | (unsigned)q;
    } else {
        int o = atomicAdd(ovfcnt, 1);
        if (o < OVFCAP) ovf[o] = make_int4(r, c, q, 0);
    }
}

// dinv[i] = rsqrt(sum of bucket weights (+ ovf entries if cnt>CAP) + 1).
__global__ void degfin_kernel(const unsigned* __restrict__ slot, const int* __restrict__ cnt,
                              const int4* __restrict__ ovf, const int* __restrict__ ovfcnt,
                              float* __restrict__ dinv, int N) {
    const int w = threadIdx.x >> 6, lane = threadIdx.x & 63;
    const int i = blockIdx.x * 4 + w;
    if (i >= N) return;
    int mraw = cnt[i];
    int m = mraw > CAP ? CAP : mraw;
    float v = 0.f;
    if (lane < m) v = (float)(slot[(size_t)i * CAP + lane] & 32767u);
    if (mraw > CAP) {
        int oc = *ovfcnt; if (oc > OVFCAP) oc = OVFCAP;
        for (int k = lane; k < oc; k += 64)
            if (ovf[k].y == i) v += (float)ovf[k].z;
    }
    #pragma unroll
    for (int off = 1; off < 64; off <<= 1) v += __shfl_xor(v, off);
    if (lane == 0) dinv[i] = rsqrtf(v * (1.0f / 32768.0f) + 1.0f);
}

// outbf[slice][M][32] (bf16) = (A[M][128] @ W[128][BN]) * dinv[row] * 2^-15.
template <int BN, int S>
__global__ void gemm_kernel(const float* __restrict__ A, const float* __restrict__ W,
                            const float* __restrict__ dinv, unsigned short* __restrict__ outbf,
                            int M) {
    constexpr int K = 128;
    constexpr int BK = 32;
    constexpr int CG = BN / 4;
    constexpr int RG = 256 / CG;
    constexpr int BM = RG * 4;
    __shared__ float xs[BM][BK + 4];
    __shared__ float ws[BK][BN];
    const int t = threadIdx.x;
    const int cg = t % CG, rg = t / CG;
    const int c0 = cg * 4, r0 = rg * 4;
    const int rowBase = blockIdx.x * BM;
    float acc[4][4] = {};
    for (int k0 = 0; k0 < K; k0 += BK) {
        constexpr int XL = BM * BK / (256 * 4);
        #pragma unroll
        for (int i = 0; i < XL; ++i) {
            int f = (t + i * 256) * 4;
            int rr = f / BK, kk = f % BK;
            int grow = rowBase + rr;
            float4 v = (grow < M) ? *(const float4*)&A[(size_t)grow * K + k0 + kk]
                                  : make_float4(0.f, 0.f, 0.f, 0.f);
            *(float4*)&xs[rr][kk] = v;
        }
        constexpr int WL = BK * BN / (256 * 4);
        #pragma unroll
        for (int i = 0; i < WL; ++i) {
            int f = (t + i * 256) * 4;
            int kk = f / BN, cc = f % BN;
            *(float4*)&ws[kk][cc] = *(const float4*)&W[(size_t)(k0 + kk) * BN + cc];
        }
        __syncthreads();
        #pragma unroll
        for (int kk = 0; kk < BK; ++kk) {
            float4 wv = *(float4*)&ws[kk][c0];
            float xv[4];
            #pragma unroll
            for (int i = 0; i < 4; ++i) xv[i] = xs[r0 + i][kk];
            #pragma unroll
            for (int i = 0; i < 4; ++i) {
                acc[i][0] += xv[i] * wv.x;
                acc[i][1] += xv[i] * wv.y;
                acc[i][2] += xv[i] * wv.z;
                acc[i][3] += xv[i] * wv.w;
            }
        }
        __syncthreads();
    }
    const int slice = c0 >> 5, cw = c0 & 31;
    #pragma unroll
    for (int i = 0; i < 4; ++i) {
        int grow = rowBase + r0 + i;
        if (grow < M) {
            float s = dinv[grow] * (1.0f / 32768.0f);
            unsigned p0 = (unsigned)f2bf(acc[i][0] * s) | ((unsigned)f2bf(acc[i][1] * s) << 16);
            unsigned p1 = (unsigned)f2bf(acc[i][2] * s) | ((unsigned)f2bf(acc[i][3] * s) << 16);
            *(uint2*)&outbf[((size_t)slice * M + grow) * 32 + cw] = make_uint2(p0, p1);
        }
    }
}

// Sliced bf16 aggregation with LDS-staged buckets. Block covers 16 nodes;
// staging: thread t loads uint4 of bucket t/16 at offset (t%16)*4 -- one
// coalesced 256B burst per bucket. Wave: 4 nodes x 4 edges-in-flight x
// 4 lanes/edge (uint4 = 8 bf16). Edge records come from LDS (4-lane
// broadcast, stride-68 pad -> conflict-free). Table prescaled by
// dinv[row]*2^-15. Epilogue: relu(d*acc + self*(d*32768) + b) in fp32.
template <int F, int S>
__global__ void gather_kernel(const unsigned short* __restrict__ xsb,
                              const unsigned* __restrict__ slot,
                              const int* __restrict__ cnt, const float* __restrict__ dinv,
                              const float* __restrict__ b, const int4* __restrict__ ovf,
                              const int* __restrict__ ovfcnt, float* __restrict__ out, int N) {
    constexpr int EPN = 4;           // edges in flight per node
    __shared__ unsigned sbkt[16 * BSTR];
    const int slice = blockIdx.x % S;
    const int grp = blockIdx.x / S;
    const int t = threadIdx.x;
    const int node0 = grp * 16;
    {   // stage 16 buckets (coalesced): thread t -> bucket t/16, chunk t%16
        int ndl = t >> 4, part = t & 15;
        int snode = node0 + ndl; if (snode >= N) snode = N - 1;
        *(uint4*)&sbkt[ndl * BSTR + part * 4] =
            *(const uint4*)&slot[(size_t)snode * CAP + part * 4];
    }
    __syncthreads();
    const int w = t >> 6, lane = t & 63;
    const int cg = lane & 3;
    const int e  = (lane >> 2) & 3;
    const int nd = lane >> 4;
    const int ndl = w * 4 + nd;          // local node 0..15
    const int i = node0 + ndl;
    const bool iv = (i < N);
    const int ic = iv ? i : 0;
    const uint4* xs4 = (const uint4*)(xsb + (size_t)slice * N * 32);
    int mraw = iv ? cnt[ic] : 0;
    int m = mraw > CAP ? CAP : mraw;
    const unsigned* lb = &sbkt[ndl * BSTR];
    float acc[8] = {};
    int j = e;
    for (; j + EPN < m; j += 2 * EPN) {
        unsigned u0 = lb[j], u1 = lb[j + EPN];
        float c0 = (float)(u0 & 32767u), c1 = (float)(u1 & 32767u);
        uint4 a0 = xs4[(size_t)(u0 >> 15) * 4 + cg];
        uint4 a1 = xs4[(size_t)(u1 >> 15) * 4 + cg];
        acc[0] += __uint_as_float(a0.x << 16) * c0 + __uint_as_float(a1.x << 16) * c1;
        acc[1] += __uint_as_float(a0.x & 0xFFFF0000u) * c0 + __uint_as_float(a1.x & 0xFFFF0000u) * c1;
        acc[2] += __uint_as_float(a0.y << 16) * c0 + __uint_as_float(a1.y << 16) * c1;
        acc[3] += __uint_as_float(a0.y & 0xFFFF0000u) * c0 + __uint_as_float(a1.y & 0xFFFF0000u) * c1;
        acc[4] += __uint_as_float(a0.z << 16) * c0 + __uint_as_float(a1.z << 16) * c1;
        acc[5] += __uint_as_float(a0.z & 0xFFFF0000u) * c0 + __uint_as_float(a1.z & 0xFFFF0000u) * c1;
        acc[6] += __uint_as_float(a0.w << 16) * c0 + __uint_as_float(a1.w << 16) * c1;
        acc[7] += __uint_as_float(a0.w & 0xFFFF0000u) * c0 + __uint_as_float(a1.w & 0xFFFF0000u) * c1;
    }
    if (j < m) {
        unsigned u = lb[j];
        float c = (float)(u & 32767u);
        uint4 a = xs4[(size_t)(u >> 15) * 4 + cg];
        acc[0] += __uint_as_float(a.x << 16) * c;
        acc[1] += __uint_as_float(a.x & 0xFFFF0000u) * c;
        acc[2] += __uint_as_float(a.y << 16) * c;
        acc[3] += __uint_as_float(a.y & 0xFFFF0000u) * c;
        acc[4] += __uint_as_float(a.z << 16) * c;
        acc[5] += __uint_as_float(a.z & 0xFFFF0000u) * c;
        acc[6] += __uint_as_float(a.w << 16) * c;
        acc[7] += __uint_as_float(a.w & 0xFFFF0000u) * c;
    }
    if (mraw > CAP) {                     // inline overflow (normally skipped)
        int oc = *ovfcnt; if (oc > OVFCAP) oc = OVFCAP;
        for (int k = e; k < oc; k += EPN) {
            int4 r4 = ovf[k];
            if (r4.y == i) {
                float c = (float)r4.z;
                uint4 a = xs4[(size_t)r4.x * 4 + cg];
                acc[0] += __uint_as_float(a.x << 16) * c;
                acc[1] += __uint_as_float(a.x & 0xFFFF0000u) * c;
                acc[2] += __uint_as_float(a.y << 16) * c;
                acc[3] += __uint_as_float(a.y & 0xFFFF0000u) * c;
                acc[4] += __uint_as_float(a.z << 16) * c;
                acc[5] += __uint_as_float(a.z & 0xFFFF0000u) * c;
                acc[6] += __uint_as_float(a.w << 16) * c;
                acc[7] += __uint_as_float(a.w & 0xFFFF0000u) * c;
            }
        }
    }
    #pragma unroll
    for (int k = 0; k < 8; ++k) {
        acc[k] += __shfl_xor(acc[k], 4);
        acc[k] += __shfl_xor(acc[k], 8);
    }
    if (e == 0 && iv) {
        float d = dinv[i];
        float sd = d * 32768.0f;
        uint4 sv = xs4[(size_t)i * 4 + cg];
        float s0 = __uint_as_float(sv.x << 16), s1 = __uint_as_float(sv.x & 0xFFFF0000u);
        float s2 = __uint_as_float(sv.y << 16), s3 = __uint_as_float(sv.y & 0xFFFF0000u);
        float s4 = __uint_as_float(sv.z << 16), s5 = __uint_as_float(sv.z & 0xFFFF0000u);
        float s6 = __uint_as_float(sv.w << 16), s7 = __uint_as_float(sv.w & 0xFFFF0000u);
        const float* bb = &b[slice * 32 + cg * 8];
        float4 bb0 = *(const float4*)&bb[0];
        float4 bb1 = *(const float4*)&bb[4];
        float4 o0, o1;
        o0.x = fmaxf(acc[0] * d + s0 * sd + bb0.x, 0.f);
        o0.y = fmaxf(acc[1] * d + s1 * sd + bb0.y, 0.f);
        o0.z = fmaxf(acc[2] * d + s2 * sd + bb0.z, 0.f);
        o0.w = fmaxf(acc[3] * d + s3 * sd + bb0.w, 0.f);
        o1.x = fmaxf(acc[4] * d + s4 * sd + bb1.x, 0.f);
        o1.y = fmaxf(acc[5] * d + s5 * sd + bb1.y, 0.f);
        o1.z = fmaxf(acc[6] * d + s6 * sd + bb1.z, 0.f);
        o1.w = fmaxf(acc[7] * d + s7 * sd + bb1.w, 0.f);
        float* dst = &out[(size_t)i * F + slice * 32 + cg * 8];
        *(float4*)&dst[0] = o0;
        *(float4*)&dst[4] = o1;
    }
}

// sums[batch[n]] += x1[n]; cnt[batch[n]] += 1 (sorted batch, boundary atomics)
__global__ void pool_kernel(const float* __restrict__ x1, const int* __restrict__ batch,
                            float* __restrict__ sums, float* __restrict__ cnt, int N) {
    constexpr int QG = 16, S = 16, ITER = 16;
    int t = threadIdx.x;
    int q = t % QG, s = t / QG;
    int n0 = blockIdx.x * (S * ITER) + s * ITER;
    float4 acc = make_float4(0.f, 0.f, 0.f, 0.f);
    float cacc = 0.f;
    int gcur = -1;
    for (int i = 0; i < ITER; ++i) {
        int n = n0 + i;
        if (n >= N) break;
        int gid = batch[n];
        if (gid != gcur) {
            if (gcur >= 0) {
                float* dst = &sums[gcur * 64 + q * 4];
                atomicAdd(dst + 0, acc.x);
                atomicAdd(dst + 1, acc.y);
                atomicAdd(dst + 2, acc.z);
                atomicAdd(dst + 3, acc.w);
                if (q == 0) atomicAdd(&cnt[gcur], cacc);
            }
            gcur = gid;
            acc = make_float4(0.f, 0.f, 0.f, 0.f);
            cacc = 0.f;
        }
        float4 a = ((const float4*)x1)[n * QG + q];
        acc.x += a.x; acc.y += a.y; acc.z += a.z; acc.w += a.w;
        if (q == 0) cacc += 1.f;
    }
    if (gcur >= 0) {
        float* dst = &sums[gcur * 64 + q * 4];
        atomicAdd(dst + 0, acc.x);
        atomicAdd(dst + 1, acc.y);
        atomicAdd(dst + 2, acc.z);
        atomicAdd(dst + 3, acc.w);
        if (q == 0) atomicAdd(&cnt[gcur], cacc);
    }
}

// Final MLP head + log_softmax, one block. G=64 graphs.
__global__ void head_kernel(const float* __restrict__ sums, const float* __restrict__ cnt,
                            const float* __restrict__ fc1W, const float* __restrict__ fc1b,
                            const float* __restrict__ fc2W, const float* __restrict__ fc2b,
                            float* __restrict__ out) {
    __shared__ float x2[64 * 64];
    __shared__ float h[64 * 128];
    __shared__ float logits[64 * 2];
    int t = threadIdx.x;
    for (int i = t; i < 64 * 64; i += 256) {
        int g = i / 64;
        x2[i] = sums[i] / fmaxf(cnt[g], 1.f);
    }
    __syncthreads();
    for (int i = t; i < 64 * 128; i += 256) {
        int g = i / 128, k = i % 128;
        float a = fc1b[k];
        #pragma unroll 8
        for (int j = 0; j < 64; ++j) a += x2[g * 64 + j] * fc1W[j * 128 + k];
        h[i] = fmaxf(a, 0.f);
    }
    __syncthreads();
    if (t < 128) {
        int g = t / 2, m = t % 2;
        float a = fc2b[m];
        #pragma unroll 8
        for (int k = 0; k < 128; ++k) a += h[g * 128 + k] * fc2W[k * 2 + m];
        logits[t] = a;
    }
    __syncthreads();
    if (t < 128) {
        int g = t / 2, m = t % 2;
        float l0 = logits[g * 2 + 0], l1 = logits[g * 2 + 1];
        float mx = fmaxf(l0, l1);
        float lse = mx + logf(expf(l0 - mx) + expf(l1 - mx));
        out[t] = (m == 0 ? l0 : l1) - lse;
    }
}

extern "C" void kernel_launch(void* const* d_in, const int* in_sizes, int n_in,
                              void* d_out, int out_size, void* d_ws, size_t ws_size,
                              hipStream_t stream) {
    const float* x      = (const float*)d_in[0];
    const int*   eidx   = (const int*)d_in[1];
    const float* ew     = (const float*)d_in[2];
    const int*   batch  = (const int*)d_in[3];
    const float* W1     = (const float*)d_in[4];
    const float* b1     = (const float*)d_in[5];
    const float* W2     = (const float*)d_in[6];
    const float* b2     = (const float*)d_in[7];
    const float* fc1W   = (const float*)d_in[8];
    const float* fc1b   = (const float*)d_in[9];
    const float* fc2W   = (const float*)d_in[10];
    const float* fc2b   = (const float*)d_in[11];
    float* out = (float*)d_out;

    const int N = in_sizes[3];          // 50000 nodes
    const int E = in_sizes[2];          // 1600000 edges
    const int* rows = eidx;
    const int* cols = eidx + E;
    const int NR = (N + 7) / 8;
    const int RSEG = E / 8 + 32768;

    float* ws = (float*)d_ws;
    size_t off = 0;
    auto alloc = [&](size_t n) { float* p = ws + off; off += (n + 15) & ~(size_t)15; return p; };
    // --- zero-initialized region ---
    float*    sums     = alloc(64 * 64);
    float*    cntf     = alloc(16);
    int*      ovfcnt   = (int*)alloc(16);
    int*      rangeCnt = (int*)alloc(16);
    int*      cnt      = (int*)alloc(N);          // zeroed for fallback path only
    size_t zfloats = off;
    // --- rest ---
    float*    dinv   = alloc(N);
    unsigned* slot   = (unsigned*)alloc((size_t)N * CAP);
    int4*     ovf    = (int4*)alloc((size_t)OVFCAP * 4);
    float*    bufA   = alloc((size_t)N * 128);   // h2d | xw1bf | xw2bf + x1
    float*    bufB   = alloc((size_t)N * 128);   // rng | h
    int*            h2d   = (int*)bufA;                       // 8*PCH*NR ints, dead before xw1bf
    unsigned short* xw1bf = (unsigned short*)bufA;            // [4][N][32] bf16
    unsigned short* xw2bf = (unsigned short*)bufA;            // [2][N][32] bf16
    float*          x1    = bufA + (size_t)N * 32;            // after xw2bf (N*64 ushorts)
    uint2*          rng   = (uint2*)bufB;                     // 8*RSEG uint2, dead before h
    float*          h     = bufB;
    (void)ws_size;

    hipMemsetAsync(d_ws, 0, zfloats * sizeof(float), stream);

    // CSR build: partition -> histogram -> prefix -> place (no contended atomics)
    if (NR <= MAXNR) {
        part_kernel<<<256, 256, 0, stream>>>(rows, cols, ew, rangeCnt, rng, E, NR, RSEG);
        hist2_kernel<<<8 * PCH, 1024, 0, stream>>>(rng, rangeCnt, h2d, NR, RSEG);
        scan2_kernel<<<(N + 255) / 256, 256, 0, stream>>>(h2d, cnt, NR, N);
        place2_kernel<<<8 * PCH, 1024, 0, stream>>>(rng, rangeCnt, h2d, slot, ovf, ovfcnt, NR, RSEG);
    } else {
        place_simple_kernel<<<(E + 255) / 256, 256, 0, stream>>>(rows, cols, ew, cnt, slot, ovf, ovfcnt, E);
    }
    degfin_kernel<<<(N + 3) / 4, 256, 0, stream>>>(slot, cnt, ovf, ovfcnt, dinv, N);

    // Layer 1: bf16 table, 4 slices of 32 features (3.2MB per XCD-group)
    gemm_kernel<128, 4><<<(N + 31) / 32, 256, 0, stream>>>(x, W1, dinv, xw1bf, N);
    gather_kernel<128, 4><<<((N + 15) / 16) * 4, 256, 0, stream>>>(xw1bf, slot, cnt, dinv, b1, ovf, ovfcnt, h, N);

    // Layer 2: bf16 table, 2 slices of 32 features
    gemm_kernel<64, 2><<<(N + 63) / 64, 256, 0, stream>>>(h, W2, dinv, xw2bf, N);
    gather_kernel<64, 2><<<((N + 15) / 16) * 2, 256, 0, stream>>>(xw2bf, slot, cnt, dinv, b2, ovf, ovfcnt, x1, N);

    // Mean-pool + head
    pool_kernel<<<(N + 255) / 256, 256, 0, stream>>>(x1, batch, sums, cntf, N);
    head_kernel<<<1, 256, 0, stream>>>(sums, cntf, fc1W, fc1b, fc2W, fc2b, out);
}

// Round 11
// 312.838 us; speedup vs baseline: 1.2697x; 1.0927x over previous
//
#include <hip/hip_runtime.h>
#include <hip/hip_bf16.h>

// ---------------------------------------------------------------------------
// GCN: h = relu(GCNConv(x,W1,b1)); x1 = relu(GCNConv(h,W2,b2));
//      x2 = meanpool(x1,batch); out = log_softmax(relu(x2@fc1+b)@fc2+b)
//
// R11: gather tables in fp8 e4m3 (scaled by dinv[row]; 2^-15 stays in the
// epilogue so fp8 never underflows). 64B line = 64 features -> layer1 2
// slices, layer2 1 slice (edge-line traffic halves vs R10 bf16); decode via
// native v_cvt_pk_f32_fp8 (1 inst / 2 features, ~2x less VALU). degfin
// removed: hist2 accumulates q15 weight sums, scan2 emits dinv directly.
// Accuracy: fp8 3% per message, mean-pool over ~780 nodes -> logits ~1e-3.
// ---------------------------------------------------------------------------

#define CAP 64
#define OVFCAP 8192
#define MAXNR 6400   // max nodes per range (LDS histogram)
#define PCH 32       // chunks per range in the place pipeline
#define BSTR 68      // LDS bucket stride (words)

typedef float v2f __attribute__((ext_vector_type(2)));

__device__ inline void fp8x4_to_f32(unsigned w, float* o) {
    v2f lo = __builtin_amdgcn_cvt_pk_f32_fp8((int)w, false);
    v2f hi = __builtin_amdgcn_cvt_pk_f32_fp8((int)w, true);
    o[0] = lo[0]; o[1] = lo[1]; o[2] = hi[0]; o[3] = hi[1];
}
__device__ inline unsigned f32x4_to_fp8(float a, float b, float c, float d) {
    int w = 0;
    w = __builtin_amdgcn_cvt_pk_fp8_f32(a, b, w, false);
    w = __builtin_amdgcn_cvt_pk_fp8_f32(c, d, w, true);
    return (unsigned)w;
}

// P1: partition edges into 8 per-range lists rng[r] of (col, row<<15|q15(ew)).
__global__ void part_kernel(const int* __restrict__ rows, const int* __restrict__ cols,
                            const float* __restrict__ ew, int* __restrict__ rangeCnt,
                            uint2* __restrict__ rng, int E, int NR, int RSEG) {
    __shared__ int hc[8];
    const int t = threadIdx.x;
    const int nb = gridDim.x;
    const int CS = (E + nb - 1) / nb;
    const int e0 = blockIdx.x * CS, e1 = min(e0 + CS, E);
    if (t < 8) hc[t] = 0;
    __syncthreads();
    for (int e = e0 + t; e < e1; e += 256) {
        int r = cols[e] / NR;
        atomicAdd(&hc[r], 1);
    }
    __syncthreads();
    if (t < 8) hc[t] = atomicAdd(&rangeCnt[t], hc[t]);   // hc becomes cursor base
    __syncthreads();
    for (int e = e0 + t; e < e1; e += 256) {
        int c = cols[e];
        int r = c / NR;
        int q = (int)(ew[e] * 32768.0f);
        if (q > 32767) q = 32767;
        unsigned rec = ((unsigned)rows[e] << 15) | (unsigned)q;
        int pos = atomicAdd(&hc[r], 1);
        if (pos < RSEG) rng[(size_t)r * RSEG + pos] = make_uint2((unsigned)c, rec);
    }
}

// P2a: per-(range,chunk) LDS histogram + q15 weight sum
__global__ __launch_bounds__(1024)
void hist2_kernel(const uint2* __restrict__ rng, const int* __restrict__ rangeCnt,
                  int* __restrict__ h2d, int* __restrict__ w2d, int NR, int RSEG) {
    __shared__ int hist[MAXNR];
    __shared__ int wsum[MAXNR];
    const int r = blockIdx.x & 7, j = blockIdx.x >> 3;
    const int t = threadIdx.x;
    const int M = min(rangeCnt[r], RSEG);
    const int CS = (M + PCH - 1) / PCH;
    const int e0 = j * CS, e1 = min(e0 + CS, M);
    for (int n = t; n < NR; n += 1024) { hist[n] = 0; wsum[n] = 0; }
    __syncthreads();
    const uint2* lst = rng + (size_t)r * RSEG;
    for (int k = e0 + t; k < e1; k += 1024) {
        unsigned c = lst[k].x - r * NR;
        atomicAdd(&hist[c], 1);
        atomicAdd(&wsum[c], (int)(lst[k].y & 32767u));
    }
    __syncthreads();
    int* dst = h2d + (size_t)(r * PCH + j) * NR;
    int* wdst = w2d + (size_t)(r * PCH + j) * NR;
    for (int n = t; n < NR; n += 1024) { dst[n] = hist[n]; wdst[n] = wsum[n]; }
}

// P2b: per-node exclusive prefix -> bases in h2d, total -> cnt, dinv from wsum.
__global__ void scan2_kernel(int* __restrict__ h2d, const int* __restrict__ w2d,
                             int* __restrict__ cnt, float* __restrict__ dinv, int NR, int N) {
    int n = blockIdx.x * 256 + threadIdx.x;
    if (n >= N) return;
    int r = n / NR, c = n - r * NR;
    int* col = h2d + (size_t)(r * PCH) * NR + c;
    const int* wcol = w2d + (size_t)(r * PCH) * NR + c;
    int run = 0;
    long long ws = 0;
    #pragma unroll 8
    for (int j = 0; j < PCH; ++j) {
        int v = col[(size_t)j * NR];
        col[(size_t)j * NR] = run;
        run += v;
        ws += wcol[(size_t)j * NR];
    }
    cnt[n] = run;
    dinv[n] = rsqrtf((float)ws * (1.0f / 32768.0f) + 1.0f);
}

// P2c: write slot records at deterministic positions (chunk base + LDS cursor).
__global__ __launch_bounds__(1024)
void place2_kernel(const uint2* __restrict__ rng, const int* __restrict__ rangeCnt,
                   const int* __restrict__ h2d, unsigned* __restrict__ slot,
                   int4* __restrict__ ovf, int* __restrict__ ovfcnt,
                   int NR, int RSEG) {
    __shared__ int cur[MAXNR];
    const int r = blockIdx.x & 7, j = blockIdx.x >> 3;
    const int t = threadIdx.x;
    const int M = min(rangeCnt[r], RSEG);
    const int CS = (M + PCH - 1) / PCH;
    const int e0 = j * CS, e1 = min(e0 + CS, M);
    const int* src = h2d + (size_t)(r * PCH + j) * NR;
    for (int n = t; n < NR; n += 1024) cur[n] = src[n];
    __syncthreads();
    const uint2* lst = rng + (size_t)r * RSEG;
    for (int k = e0 + t; k < e1; k += 1024) {
        uint2 u2 = lst[k];
        int pos = atomicAdd(&cur[u2.x - r * NR], 1);   // LDS cursor
        if (pos < CAP) {
            slot[(size_t)u2.x * CAP + pos] = u2.y;
        } else {
            int o = atomicAdd(ovfcnt, 1);
            if (o < OVFCAP)
                ovf[o] = make_int4((int)(u2.y >> 15), (int)u2.x, (int)(u2.y & 32767u), 0);
        }
    }
}

// Fallback for N too large for LDS histogram (not taken here).
__global__ void place_simple_kernel(const int* __restrict__ rows, const int* __restrict__ cols,
                                    const float* __restrict__ ew, int* __restrict__ cnt,
                                    unsigned* __restrict__ slot, int4* __restrict__ ovf,
                                    int* __restrict__ ovfcnt, int E) {
    int e = blockIdx.x * 256 + threadIdx.x;
    if (e >= E) return;
    int r = rows[e], c = cols[e];
    int q = (int)(ew[e] * 32768.0f);
    if (q > 32767) q = 32767;
    int pos = atomicAdd(&cnt[c], 1);
    if (pos < CAP) {
        slot[(size_t)c * CAP + pos] = ((unsigned)r << 15) | (unsigned)q;
    } else {
        int o = atomicAdd(ovfcnt, 1);
        if (o < OVFCAP) ovf[o] = make_int4(r, c, q, 0);
    }
}

// Fallback-path dinv (normal path computes dinv in scan2).
__global__ void degfin_kernel(const unsigned* __restrict__ slot, const int* __restrict__ cnt,
                              const int4* __restrict__ ovf, const int* __restrict__ ovfcnt,
                              float* __restrict__ dinv, int N) {
    const int w = threadIdx.x >> 6, lane = threadIdx.x & 63;
    const int i = blockIdx.x * 4 + w;
    if (i >= N) return;
    int mraw = cnt[i];
    int m = mraw > CAP ? CAP : mraw;
    float v = 0.f;
    if (lane < m) v = (float)(slot[(size_t)i * CAP + lane] & 32767u);
    if (mraw > CAP) {
        int oc = *ovfcnt; if (oc > OVFCAP) oc = OVFCAP;
        for (int k = lane; k < oc; k += 64)
            if (ovf[k].y == i) v += (float)ovf[k].z;
    }
    #pragma unroll
    for (int off = 1; off < 64; off <<= 1) v += __shfl_xor(v, off);
    if (lane == 0) dinv[i] = rsqrtf(v * (1.0f / 32768.0f) + 1.0f);
}

// outf8[slice][M][64] (fp8 e4m3) = (A[M][128] @ W[128][BN]) * dinv[row].
// (2^-15 coef scale is applied in the gather epilogue, not here.)
template <int BN, int S>
__global__ void gemm_kernel(const float* __restrict__ A, const float* __restrict__ W,
                            const float* __restrict__ dinv, unsigned char* __restrict__ outf8,
                            int M) {
    constexpr int K = 128;
    constexpr int BK = 32;
    constexpr int CG = BN / 4;
    constexpr int RG = 256 / CG;
    constexpr int BM = RG * 4;
    __shared__ float xs[BM][BK + 4];
    __shared__ float ws[BK][BN];
    const int t = threadIdx.x;
    const int cg = t % CG, rg = t / CG;
    const int c0 = cg * 4, r0 = rg * 4;
    const int rowBase = blockIdx.x * BM;
    float acc[4][4] = {};
    for (int k0 = 0; k0 < K; k0 += BK) {
        constexpr int XL = BM * BK / (256 * 4);
        #pragma unroll
        for (int i = 0; i < XL; ++i) {
            int f = (t + i * 256) * 4;
            int rr = f / BK, kk = f % BK;
            int grow = rowBase + rr;
            float4 v = (grow < M) ? *(const float4*)&A[(size_t)grow * K + k0 + kk]
                                  : make_float4(0.f, 0.f, 0.f, 0.f);
            *(float4*)&xs[rr][kk] = v;
        }
        constexpr int WL = BK * BN / (256 * 4);
        #pragma unroll
        for (int i = 0; i < WL; ++i) {
            int f = (t + i * 256) * 4;
            int kk = f / BN, cc = f % BN;
            *(float4*)&ws[kk][cc] = *(const float4*)&W[(size_t)(k0 + kk) * BN + cc];
        }
        __syncthreads();
        #pragma unroll
        for (int kk = 0; kk < BK; ++kk) {
            float4 wv = *(float4*)&ws[kk][c0];
            float xv[4];
            #pragma unroll
            for (int i = 0; i < 4; ++i) xv[i] = xs[r0 + i][kk];
            #pragma unroll
            for (int i = 0; i < 4; ++i) {
                acc[i][0] += xv[i] * wv.x;
                acc[i][1] += xv[i] * wv.y;
                acc[i][2] += xv[i] * wv.z;
                acc[i][3] += xv[i] * wv.w;
            }
        }
        __syncthreads();
    }
    const int slice = c0 >> 6, cw = c0 & 63;
    #pragma unroll
    for (int i = 0; i < 4; ++i) {
        int grow = rowBase + r0 + i;
        if (grow < M) {
            float s = dinv[grow];
            unsigned w = f32x4_to_fp8(acc[i][0] * s, acc[i][1] * s, acc[i][2] * s, acc[i][3] * s);
            *(unsigned*)&outf8[((size_t)slice * M + grow) * 64 + cw] = w;
        }
    }
}

// Sliced fp8 aggregation with LDS-staged buckets. Block covers 16 nodes;
// wave: 4 nodes x 4 edges-in-flight x 4 lanes/edge (uint4 = 16 fp8). Table
// prescaled by dinv[row]; coef = (float)q15; epilogue applies d*2^-15 to the
// edge sum and d to the fp8 self term: relu(acc*d/32768 + self*d + b).
template <int F, int S>
__global__ void gather_kernel(const unsigned char* __restrict__ xsb,
                              const unsigned* __restrict__ slot,
                              const int* __restrict__ cnt, const float* __restrict__ dinv,
                              const float* __restrict__ b, const int4* __restrict__ ovf,
                              const int* __restrict__ ovfcnt, float* __restrict__ out, int N) {
    constexpr int EPN = 4;           // edges in flight per node
    __shared__ unsigned sbkt[16 * BSTR];
    const int slice = (S > 1) ? (blockIdx.x % S) : 0;
    const int grp = (S > 1) ? (blockIdx.x / S) : blockIdx.x;
    const int t = threadIdx.x;
    const int node0 = grp * 16;
    {   // stage 16 buckets (coalesced): thread t -> bucket t/16, chunk t%16
        int ndl = t >> 4, part = t & 15;
        int snode = node0 + ndl; if (snode >= N) snode = N - 1;
        *(uint4*)&sbkt[ndl * BSTR + part * 4] =
            *(const uint4*)&slot[(size_t)snode * CAP + part * 4];
    }
    __syncthreads();
    const int w = t >> 6, lane = t & 63;
    const int cg = lane & 3;
    const int e  = (lane >> 2) & 3;
    const int nd = lane >> 4;
    const int ndl = w * 4 + nd;          // local node 0..15
    const int i = node0 + ndl;
    const bool iv = (i < N);
    const int ic = iv ? i : 0;
    const uint4* xs4 = (const uint4*)(xsb + (size_t)slice * N * 64);
    int mraw = iv ? cnt[ic] : 0;
    int m = mraw > CAP ? CAP : mraw;
    const unsigned* lb = &sbkt[ndl * BSTR];
    float acc[16] = {};
    int j = e;
    for (; j + EPN < m; j += 2 * EPN) {
        unsigned u0 = lb[j], u1 = lb[j + EPN];
        float c0 = (float)(u0 & 32767u), c1 = (float)(u1 & 32767u);
        uint4 a0 = xs4[(size_t)(u0 >> 15) * 4 + cg];
        uint4 a1 = xs4[(size_t)(u1 >> 15) * 4 + cg];
        float f0[16], f1[16];
        fp8x4_to_f32(a0.x, f0 + 0);  fp8x4_to_f32(a0.y, f0 + 4);
        fp8x4_to_f32(a0.z, f0 + 8);  fp8x4_to_f32(a0.w, f0 + 12);
        fp8x4_to_f32(a1.x, f1 + 0);  fp8x4_to_f32(a1.y, f1 + 4);
        fp8x4_to_f32(a1.z, f1 + 8);  fp8x4_to_f32(a1.w, f1 + 12);
        #pragma unroll
        for (int k = 0; k < 16; ++k) acc[k] += f0[k] * c0 + f1[k] * c1;
    }
    if (j < m) {
        unsigned u = lb[j];
        float c = (float)(u & 32767u);
        uint4 a = xs4[(size_t)(u >> 15) * 4 + cg];
        float f[16];
        fp8x4_to_f32(a.x, f + 0);  fp8x4_to_f32(a.y, f + 4);
        fp8x4_to_f32(a.z, f + 8);  fp8x4_to_f32(a.w, f + 12);
        #pragma unroll
        for (int k = 0; k < 16; ++k) acc[k] += f[k] * c;
    }
    if (mraw > CAP) {                     // inline overflow (normally skipped)
        int oc = *ovfcnt; if (oc > OVFCAP) oc = OVFCAP;
        for (int k = e; k < oc; k += EPN) {
            int4 r4 = ovf[k];
            if (r4.y == i) {
                float c = (float)r4.z;
                uint4 a = xs4[(size_t)r4.x * 4 + cg];
                float f[16];
                fp8x4_to_f32(a.x, f + 0);  fp8x4_to_f32(a.y, f + 4);
                fp8x4_to_f32(a.z, f + 8);  fp8x4_to_f32(a.w, f + 12);
                #pragma unroll
                for (int kk = 0; kk < 16; ++kk) acc[kk] += f[kk] * c;
            }
        }
    }
    #pragma unroll
    for (int k = 0; k < 16; ++k) {
        acc[k] += __shfl_xor(acc[k], 4);
        acc[k] += __shfl_xor(acc[k], 8);
    }
    if (e == 0 && iv) {
        float d = dinv[i];
        float sa = d * (1.0f / 32768.0f);
        uint4 sv = xs4[(size_t)i * 4 + cg];
        float sf[16];
        fp8x4_to_f32(sv.x, sf + 0);  fp8x4_to_f32(sv.y, sf + 4);
        fp8x4_to_f32(sv.z, sf + 8);  fp8x4_to_f32(sv.w, sf + 12);
        const float* bb = &b[slice * 64 + cg * 16];
        float o[16];
        #pragma unroll
        for (int k = 0; k < 16; ++k)
            o[k] = fmaxf(acc[k] * sa + sf[k] * d + bb[k], 0.f);
        float* dst = &out[(size_t)i * F + slice * 64 + cg * 16];
        *(float4*)&dst[0]  = make_float4(o[0], o[1], o[2], o[3]);
        *(float4*)&dst[4]  = make_float4(o[4], o[5], o[6], o[7]);
        *(float4*)&dst[8]  = make_float4(o[8], o[9], o[10], o[11]);
        *(float4*)&dst[12] = make_float4(o[12], o[13], o[14], o[15]);
    }
}

// sums[batch[n]] += x1[n]; cnt[batch[n]] += 1 (sorted batch, boundary atomics)
__global__ void pool_kernel(const float* __restrict__ x1, const int* __restrict__ batch,
                            float* __restrict__ sums, float* __restrict__ cnt, int N) {
    constexpr int QG = 16, S = 16, ITER = 16;
    int t = threadIdx.x;
    int q = t % QG, s = t / QG;
    int n0 = blockIdx.x * (S * ITER) + s * ITER;
    float4 acc = make_float4(0.f, 0.f, 0.f, 0.f);
    float cacc = 0.f;
    int gcur = -1;
    for (int i = 0; i < ITER; ++i) {
        int n = n0 + i;
        if (n >= N) break;
        int gid = batch[n];
        if (gid != gcur) {
            if (gcur >= 0) {
                float* dst = &sums[gcur * 64 + q * 4];
                atomicAdd(dst + 0, acc.x);
                atomicAdd(dst + 1, acc.y);
                atomicAdd(dst + 2, acc.z);
                atomicAdd(dst + 3, acc.w);
                if (q == 0) atomicAdd(&cnt[gcur], cacc);
            }
            gcur = gid;
            acc = make_float4(0.f, 0.f, 0.f, 0.f);
            cacc = 0.f;
        }
        float4 a = ((const float4*)x1)[n * QG + q];
        acc.x += a.x; acc.y += a.y; acc.z += a.z; acc.w += a.w;
        if (q == 0) cacc += 1.f;
    }
    if (gcur >= 0) {
        float* dst = &sums[gcur * 64 + q * 4];
        atomicAdd(dst + 0, acc.x);
        atomicAdd(dst + 1, acc.y);
        atomicAdd(dst + 2, acc.z);
        atomicAdd(dst + 3, acc.w);
        if (q == 0) atomicAdd(&cnt[gcur], cacc);
    }
}

// Final MLP head + log_softmax, one block. G=64 graphs.
__global__ void head_kernel(const float* __restrict__ sums, const float* __restrict__ cnt,
                            const float* __restrict__ fc1W, const float* __restrict__ fc1b,
                            const float* __restrict__ fc2W, const float* __restrict__ fc2b,
                            float* __restrict__ out) {
    __shared__ float x2[64 * 64];
    __shared__ float h[64 * 128];
    __shared__ float logits[64 * 2];
    int t = threadIdx.x;
    for (int i = t; i < 64 * 64; i += 256) {
        int g = i / 64;
        x2[i] = sums[i] / fmaxf(cnt[g], 1.f);
    }
    __syncthreads();
    for (int i = t; i < 64 * 128; i += 256) {
        int g = i / 128, k = i % 128;
        float a = fc1b[k];
        #pragma unroll 8
        for (int j = 0; j < 64; ++j) a += x2[g * 64 + j] * fc1W[j * 128 + k];
        h[i] = fmaxf(a, 0.f);
    }
    __syncthreads();
    if (t < 128) {
        int g = t / 2, m = t % 2;
        float a = fc2b[m];
        #pragma unroll 8
        for (int k = 0; k < 128; ++k) a += h[g * 128 + k] * fc2W[k * 2 + m];
        logits[t] = a;
    }
    __syncthreads();
    if (t < 128) {
        int g = t / 2, m = t % 2;
        float l0 = logits[g * 2 + 0], l1 = logits[g * 2 + 1];
        float mx = fmaxf(l0, l1);
        float lse = mx + logf(expf(l0 - mx) + expf(l1 - mx));
        out[t] = (m == 0 ? l0 : l1) - lse;
    }
}

extern "C" void kernel_launch(void* const* d_in, const int* in_sizes, int n_in,
                              void* d_out, int out_size, void* d_ws, size_t ws_size,
                              hipStream_t stream) {
    const float* x      = (const float*)d_in[0];
    const int*   eidx   = (const int*)d_in[1];
    const float* ew     = (const float*)d_in[2];
    const int*   batch  = (const int*)d_in[3];
    const float* W1     = (const float*)d_in[4];
    const float* b1     = (const float*)d_in[5];
    const float* W2     = (const float*)d_in[6];
    const float* b2     = (const float*)d_in[7];
    const float* fc1W   = (const float*)d_in[8];
    const float* fc1b   = (const float*)d_in[9];
    const float* fc2W   = (const float*)d_in[10];
    const float* fc2b   = (const float*)d_in[11];
    float* out = (float*)d_out;

    const int N = in_sizes[3];          // 50000 nodes
    const int E = in_sizes[2];          // 1600000 edges
    const int* rows = eidx;
    const int* cols = eidx + E;
    const int NR = (N + 7) / 8;
    const int RSEG = E / 8 + 32768;

    float* ws = (float*)d_ws;
    size_t off = 0;
    auto alloc = [&](size_t n) { float* p = ws + off; off += (n + 15) & ~(size_t)15; return p; };
    // --- zero-initialized region ---
    float*    sums     = alloc(64 * 64);
    float*    cntf     = alloc(16);
    int*      ovfcnt   = (int*)alloc(16);
    int*      rangeCnt = (int*)alloc(16);
    int*      cnt      = (int*)alloc(N);          // zeroed for fallback path only
    size_t zfloats = off;
    // --- rest ---
    float*    dinv   = alloc(N);
    unsigned* slot   = (unsigned*)alloc((size_t)N * CAP);
    int4*     ovf    = (int4*)alloc((size_t)OVFCAP * 4);
    float*    bufA   = alloc((size_t)N * 128);   // h2d+w2d | xw1f8 | xw2f8 + x1
    float*    bufB   = alloc((size_t)N * 128);   // rng | h
    int*           h2d   = (int*)bufA;                        // 8*PCH*NR ints (6.4MB)
    int*           w2d   = h2d + (size_t)8 * PCH * NR;        // 8*PCH*NR ints (6.4MB)
    unsigned char* xw1f8 = (unsigned char*)bufA;              // [2][N][64] fp8 (6.4MB)
    unsigned char* xw2f8 = (unsigned char*)bufA;              // [1][N][64] fp8 (3.2MB)
    float*         x1    = bufA + (size_t)N * 32;             // [N][64] f32 at +6.4MB
    uint2*         rng   = (uint2*)bufB;                      // 8*RSEG uint2, dead before h
    float*         h     = bufB;
    (void)ws_size;

    hipMemsetAsync(d_ws, 0, zfloats * sizeof(float), stream);

    // CSR build: partition -> histogram(+wsum) -> prefix(+dinv) -> place
    if (NR <= MAXNR) {
        part_kernel<<<256, 256, 0, stream>>>(rows, cols, ew, rangeCnt, rng, E, NR, RSEG);
        hist2_kernel<<<8 * PCH, 1024, 0, stream>>>(rng, rangeCnt, h2d, w2d, NR, RSEG);
        scan2_kernel<<<(N + 255) / 256, 256, 0, stream>>>(h2d, w2d, cnt, dinv, NR, N);
        place2_kernel<<<8 * PCH, 1024, 0, stream>>>(rng, rangeCnt, h2d, slot, ovf, ovfcnt, NR, RSEG);
    } else {
        place_simple_kernel<<<(E + 255) / 256, 256, 0, stream>>>(rows, cols, ew, cnt, slot, ovf, ovfcnt, E);
        degfin_kernel<<<(N + 3) / 4, 256, 0, stream>>>(slot, cnt, ovf, ovfcnt, dinv, N);
    }

    // Layer 1: fp8 table, 2 slices of 64 features (3.2MB per XCD-group)
    gemm_kernel<128, 2><<<(N + 31) / 32, 256, 0, stream>>>(x, W1, dinv, xw1f8, N);
    gather_kernel<128, 2><<<((N + 15) / 16) * 2, 256, 0, stream>>>(xw1f8, slot, cnt, dinv, b1, ovf, ovfcnt, h, N);

    // Layer 2: fp8 table, 1 slice of 64 features (replicated read-only per XCD)
    gemm_kernel<64, 1><<<(N + 63) / 64, 256, 0, stream>>>(h, W2, dinv, xw2f8, N);
    gather_kernel<64, 1><<<(N + 15) / 16, 256, 0, stream>>>(xw2f8, slot, cnt, dinv, b2, ovf, ovfcnt, x1, N);

    // Mean-pool + head
    pool_kernel<<<(N + 255) / 256, 256, 0, stream>>>(x1, batch, sums, cntf, N);
    head_kernel<<<1, 256, 0, stream>>>(sums, cntf, fc1W, fc1b, fc2W, fc2b, out);
}

// Round 12
// 272.581 us; speedup vs baseline: 1.4572x; 1.1477x over previous
//
#include <hip/hip_runtime.h>
#include <hip/hip_bf16.h>

// ---------------------------------------------------------------------------
// GCN: h = relu(GCNConv(x,W1,b1)); x1 = relu(GCNConv(h,W2,b2));
//      x2 = meanpool(x1,batch); out = log_softmax(relu(x2@fc1+b)@fc2+b)
//
// R12: head parallelized -- R11's single-block head ran 44us at 0.04%
// occupancy (1 CU, latency-bound on fc1W global loads). Now one block per
// graph (64 blocks x 128 thr): x2 staged in LDS, h[k] per thread (coalesced
// fc1W), per-wave shfl reduction for the 2 logits. Rest unchanged from R11
// (fp8 sliced gather tables, two-phase CSR build).
// ---------------------------------------------------------------------------

#define CAP 64
#define OVFCAP 8192
#define MAXNR 6400   // max nodes per range (LDS histogram)
#define PCH 32       // chunks per range in the place pipeline
#define BSTR 68      // LDS bucket stride (words)

typedef float v2f __attribute__((ext_vector_type(2)));

__device__ inline void fp8x4_to_f32(unsigned w, float* o) {
    v2f lo = __builtin_amdgcn_cvt_pk_f32_fp8((int)w, false);
    v2f hi = __builtin_amdgcn_cvt_pk_f32_fp8((int)w, true);
    o[0] = lo[0]; o[1] = lo[1]; o[2] = hi[0]; o[3] = hi[1];
}
__device__ inline unsigned f32x4_to_fp8(float a, float b, float c, float d) {
    int w = 0;
    w = __builtin_amdgcn_cvt_pk_fp8_f32(a, b, w, false);
    w = __builtin_amdgcn_cvt_pk_fp8_f32(c, d, w, true);
    return (unsigned)w;
}

// P1: partition edges into 8 per-range lists rng[r] of (col, row<<15|q15(ew)).
__global__ void part_kernel(const int* __restrict__ rows, const int* __restrict__ cols,
                            const float* __restrict__ ew, int* __restrict__ rangeCnt,
                            uint2* __restrict__ rng, int E, int NR, int RSEG) {
    __shared__ int hc[8];
    const int t = threadIdx.x;
    const int nb = gridDim.x;
    const int CS = (E + nb - 1) / nb;
    const int e0 = blockIdx.x * CS, e1 = min(e0 + CS, E);
    if (t < 8) hc[t] = 0;
    __syncthreads();
    for (int e = e0 + t; e < e1; e += 256) {
        int r = cols[e] / NR;
        atomicAdd(&hc[r], 1);
    }
    __syncthreads();
    if (t < 8) hc[t] = atomicAdd(&rangeCnt[t], hc[t]);   // hc becomes cursor base
    __syncthreads();
    for (int e = e0 + t; e < e1; e += 256) {
        int c = cols[e];
        int r = c / NR;
        int q = (int)(ew[e] * 32768.0f);
        if (q > 32767) q = 32767;
        unsigned rec = ((unsigned)rows[e] << 15) | (unsigned)q;
        int pos = atomicAdd(&hc[r], 1);
        if (pos < RSEG) rng[(size_t)r * RSEG + pos] = make_uint2((unsigned)c, rec);
    }
}

// P2a: per-(range,chunk) LDS histogram + q15 weight sum
__global__ __launch_bounds__(1024)
void hist2_kernel(const uint2* __restrict__ rng, const int* __restrict__ rangeCnt,
                  int* __restrict__ h2d, int* __restrict__ w2d, int NR, int RSEG) {
    __shared__ int hist[MAXNR];
    __shared__ int wsum[MAXNR];
    const int r = blockIdx.x & 7, j = blockIdx.x >> 3;
    const int t = threadIdx.x;
    const int M = min(rangeCnt[r], RSEG);
    const int CS = (M + PCH - 1) / PCH;
    const int e0 = j * CS, e1 = min(e0 + CS, M);
    for (int n = t; n < NR; n += 1024) { hist[n] = 0; wsum[n] = 0; }
    __syncthreads();
    const uint2* lst = rng + (size_t)r * RSEG;
    for (int k = e0 + t; k < e1; k += 1024) {
        unsigned c = lst[k].x - r * NR;
        atomicAdd(&hist[c], 1);
        atomicAdd(&wsum[c], (int)(lst[k].y & 32767u));
    }
    __syncthreads();
    int* dst = h2d + (size_t)(r * PCH + j) * NR;
    int* wdst = w2d + (size_t)(r * PCH + j) * NR;
    for (int n = t; n < NR; n += 1024) { dst[n] = hist[n]; wdst[n] = wsum[n]; }
}

// P2b: per-node exclusive prefix -> bases in h2d, total -> cnt, dinv from wsum.
__global__ void scan2_kernel(int* __restrict__ h2d, const int* __restrict__ w2d,
                             int* __restrict__ cnt, float* __restrict__ dinv, int NR, int N) {
    int n = blockIdx.x * 256 + threadIdx.x;
    if (n >= N) return;
    int r = n / NR, c = n - r * NR;
    int* col = h2d + (size_t)(r * PCH) * NR + c;
    const int* wcol = w2d + (size_t)(r * PCH) * NR + c;
    int run = 0;
    long long ws = 0;
    #pragma unroll 8
    for (int j = 0; j < PCH; ++j) {
        int v = col[(size_t)j * NR];
        col[(size_t)j * NR] = run;
        run += v;
        ws += wcol[(size_t)j * NR];
    }
    cnt[n] = run;
    dinv[n] = rsqrtf((float)ws * (1.0f / 32768.0f) + 1.0f);
}

// P2c: write slot records at deterministic positions (chunk base + LDS cursor).
__global__ __launch_bounds__(1024)
void place2_kernel(const uint2* __restrict__ rng, const int* __restrict__ rangeCnt,
                   const int* __restrict__ h2d, unsigned* __restrict__ slot,
                   int4* __restrict__ ovf, int* __restrict__ ovfcnt,
                   int NR, int RSEG) {
    __shared__ int cur[MAXNR];
    const int r = blockIdx.x & 7, j = blockIdx.x >> 3;
    const int t = threadIdx.x;
    const int M = min(rangeCnt[r], RSEG);
    const int CS = (M + PCH - 1) / PCH;
    const int e0 = j * CS, e1 = min(e0 + CS, M);
    const int* src = h2d + (size_t)(r * PCH + j) * NR;
    for (int n = t; n < NR; n += 1024) cur[n] = src[n];
    __syncthreads();
    const uint2* lst = rng + (size_t)r * RSEG;
    for (int k = e0 + t; k < e1; k += 1024) {
        uint2 u2 = lst[k];
        int pos = atomicAdd(&cur[u2.x - r * NR], 1);   // LDS cursor
        if (pos < CAP) {
            slot[(size_t)u2.x * CAP + pos] = u2.y;
        } else {
            int o = atomicAdd(ovfcnt, 1);
            if (o < OVFCAP)
                ovf[o] = make_int4((int)(u2.y >> 15), (int)u2.x, (int)(u2.y & 32767u), 0);
        }
    }
}

// Fallback for N too large for LDS histogram (not taken here).
__global__ void place_simple_kernel(const int* __restrict__ rows, const int* __restrict__ cols,
                                    const float* __restrict__ ew, int* __restrict__ cnt,
                                    unsigned* __restrict__ slot, int4* __restrict__ ovf,
                                    int* __restrict__ ovfcnt, int E) {
    int e = blockIdx.x * 256 + threadIdx.x;
    if (e >= E) return;
    int r = rows[e], c = cols[e];
    int q = (int)(ew[e] * 32768.0f);
    if (q > 32767) q = 32767;
    int pos = atomicAdd(&cnt[c], 1);
    if (pos < CAP) {
        slot[(size_t)c * CAP + pos] = ((unsigned)r << 15) | (unsigned)q;
    } else {
        int o = atomicAdd(ovfcnt, 1);
        if (o < OVFCAP) ovf[o] = make_int4(r, c, q, 0);
    }
}

// Fallback-path dinv (normal path computes dinv in scan2).
__global__ void degfin_kernel(const unsigned* __restrict__ slot, const int* __restrict__ cnt,
                              const int4* __restrict__ ovf, const int* __restrict__ ovfcnt,
                              float* __restrict__ dinv, int N) {
    const int w = threadIdx.x >> 6, lane = threadIdx.x & 63;
    const int i = blockIdx.x * 4 + w;
    if (i >= N) return;
    int mraw = cnt[i];
    int m = mraw > CAP ? CAP : mraw;
    float v = 0.f;
    if (lane < m) v = (float)(slot[(size_t)i * CAP + lane] & 32767u);
    if (mraw > CAP) {
        int oc = *ovfcnt; if (oc > OVFCAP) oc = OVFCAP;
        for (int k = lane; k < oc; k += 64)
            if (ovf[k].y == i) v += (float)ovf[k].z;
    }
    #pragma unroll
    for (int off = 1; off < 64; off <<= 1) v += __shfl_xor(v, off);
    if (lane == 0) dinv[i] = rsqrtf(v * (1.0f / 32768.0f) + 1.0f);
}

// outf8[slice][M][64] (fp8 e4m3) = (A[M][128] @ W[128][BN]) * dinv[row].
template <int BN, int S>
__global__ void gemm_kernel(const float* __restrict__ A, const float* __restrict__ W,
                            const float* __restrict__ dinv, unsigned char* __restrict__ outf8,
                            int M) {
    constexpr int K = 128;
    constexpr int BK = 32;
    constexpr int CG = BN / 4;
    constexpr int RG = 256 / CG;
    constexpr int BM = RG * 4;
    __shared__ float xs[BM][BK + 4];
    __shared__ float ws[BK][BN];
    const int t = threadIdx.x;
    const int cg = t % CG, rg = t / CG;
    const int c0 = cg * 4, r0 = rg * 4;
    const int rowBase = blockIdx.x * BM;
    float acc[4][4] = {};
    for (int k0 = 0; k0 < K; k0 += BK) {
        constexpr int XL = BM * BK / (256 * 4);
        #pragma unroll
        for (int i = 0; i < XL; ++i) {
            int f = (t + i * 256) * 4;
            int rr = f / BK, kk = f % BK;
            int grow = rowBase + rr;
            float4 v = (grow < M) ? *(const float4*)&A[(size_t)grow * K + k0 + kk]
                                  : make_float4(0.f, 0.f, 0.f, 0.f);
            *(float4*)&xs[rr][kk] = v;
        }
        constexpr int WL = BK * BN / (256 * 4);
        #pragma unroll
        for (int i = 0; i < WL; ++i) {
            int f = (t + i * 256) * 4;
            int kk = f / BN, cc = f % BN;
            *(float4*)&ws[kk][cc] = *(const float4*)&W[(size_t)(k0 + kk) * BN + cc];
        }
        __syncthreads();
        #pragma unroll
        for (int kk = 0; kk < BK; ++kk) {
            float4 wv = *(float4*)&ws[kk][c0];
            float xv[4];
            #pragma unroll
            for (int i = 0; i < 4; ++i) xv[i] = xs[r0 + i][kk];
            #pragma unroll
            for (int i = 0; i < 4; ++i) {
                acc[i][0] += xv[i] * wv.x;
                acc[i][1] += xv[i] * wv.y;
                acc[i][2] += xv[i] * wv.z;
                acc[i][3] += xv[i] * wv.w;
            }
        }
        __syncthreads();
    }
    const int slice = c0 >> 6, cw = c0 & 63;
    #pragma unroll
    for (int i = 0; i < 4; ++i) {
        int grow = rowBase + r0 + i;
        if (grow < M) {
            float s = dinv[grow];
            unsigned w = f32x4_to_fp8(acc[i][0] * s, acc[i][1] * s, acc[i][2] * s, acc[i][3] * s);
            *(unsigned*)&outf8[((size_t)slice * M + grow) * 64 + cw] = w;
        }
    }
}

// Sliced fp8 aggregation with LDS-staged buckets (see R10/R11 notes).
template <int F, int S>
__global__ void gather_kernel(const unsigned char* __restrict__ xsb,
                              const unsigned* __restrict__ slot,
                              const int* __restrict__ cnt, const float* __restrict__ dinv,
                              const float* __restrict__ b, const int4* __restrict__ ovf,
                              const int* __restrict__ ovfcnt, float* __restrict__ out, int N) {
    constexpr int EPN = 4;           // edges in flight per node
    __shared__ unsigned sbkt[16 * BSTR];
    const int slice = (S > 1) ? (blockIdx.x % S) : 0;
    const int grp = (S > 1) ? (blockIdx.x / S) : blockIdx.x;
    const int t = threadIdx.x;
    const int node0 = grp * 16;
    {   // stage 16 buckets (coalesced): thread t -> bucket t/16, chunk t%16
        int ndl = t >> 4, part = t & 15;
        int snode = node0 + ndl; if (snode >= N) snode = N - 1;
        *(uint4*)&sbkt[ndl * BSTR + part * 4] =
            *(const uint4*)&slot[(size_t)snode * CAP + part * 4];
    }
    __syncthreads();
    const int w = t >> 6, lane = t & 63;
    const int cg = lane & 3;
    const int e  = (lane >> 2) & 3;
    const int nd = lane >> 4;
    const int ndl = w * 4 + nd;          // local node 0..15
    const int i = node0 + ndl;
    const bool iv = (i < N);
    const int ic = iv ? i : 0;
    const uint4* xs4 = (const uint4*)(xsb + (size_t)slice * N * 64);
    int mraw = iv ? cnt[ic] : 0;
    int m = mraw > CAP ? CAP : mraw;
    const unsigned* lb = &sbkt[ndl * BSTR];
    float acc[16] = {};
    int j = e;
    for (; j + EPN < m; j += 2 * EPN) {
        unsigned u0 = lb[j], u1 = lb[j + EPN];
        float c0 = (float)(u0 & 32767u), c1 = (float)(u1 & 32767u);
        uint4 a0 = xs4[(size_t)(u0 >> 15) * 4 + cg];
        uint4 a1 = xs4[(size_t)(u1 >> 15) * 4 + cg];
        float f0[16], f1[16];
        fp8x4_to_f32(a0.x, f0 + 0);  fp8x4_to_f32(a0.y, f0 + 4);
        fp8x4_to_f32(a0.z, f0 + 8);  fp8x4_to_f32(a0.w, f0 + 12);
        fp8x4_to_f32(a1.x, f1 + 0);  fp8x4_to_f32(a1.y, f1 + 4);
        fp8x4_to_f32(a1.z, f1 + 8);  fp8x4_to_f32(a1.w, f1 + 12);
        #pragma unroll
        for (int k = 0; k < 16; ++k) acc[k] += f0[k] * c0 + f1[k] * c1;
    }
    if (j < m) {
        unsigned u = lb[j];
        float c = (float)(u & 32767u);
        uint4 a = xs4[(size_t)(u >> 15) * 4 + cg];
        float f[16];
        fp8x4_to_f32(a.x, f + 0);  fp8x4_to_f32(a.y, f + 4);
        fp8x4_to_f32(a.z, f + 8);  fp8x4_to_f32(a.w, f + 12);
        #pragma unroll
        for (int k = 0; k < 16; ++k) acc[k] += f[k] * c;
    }
    if (mraw > CAP) {                     // inline overflow (normally skipped)
        int oc = *ovfcnt; if (oc > OVFCAP) oc = OVFCAP;
        for (int k = e; k < oc; k += EPN) {
            int4 r4 = ovf[k];
            if (r4.y == i) {
                float c = (float)r4.z;
                uint4 a = xs4[(size_t)r4.x * 4 + cg];
                float f[16];
                fp8x4_to_f32(a.x, f + 0);  fp8x4_to_f32(a.y, f + 4);
                fp8x4_to_f32(a.z, f + 8);  fp8x4_to_f32(a.w, f + 12);
                #pragma unroll
                for (int kk = 0; kk < 16; ++kk) acc[kk] += f[kk] * c;
            }
        }
    }
    #pragma unroll
    for (int k = 0; k < 16; ++k) {
        acc[k] += __shfl_xor(acc[k], 4);
        acc[k] += __shfl_xor(acc[k], 8);
    }
    if (e == 0 && iv) {
        float d = dinv[i];
        float sa = d * (1.0f / 32768.0f);
        uint4 sv = xs4[(size_t)i * 4 + cg];
        float sf[16];
        fp8x4_to_f32(sv.x, sf + 0);  fp8x4_to_f32(sv.y, sf + 4);
        fp8x4_to_f32(sv.z, sf + 8);  fp8x4_to_f32(sv.w, sf + 12);
        const float* bb = &b[slice * 64 + cg * 16];
        float o[16];
        #pragma unroll
        for (int k = 0; k < 16; ++k)
            o[k] = fmaxf(acc[k] * sa + sf[k] * d + bb[k], 0.f);
        float* dst = &out[(size_t)i * F + slice * 64 + cg * 16];
        *(float4*)&dst[0]  = make_float4(o[0], o[1], o[2], o[3]);
        *(float4*)&dst[4]  = make_float4(o[4], o[5], o[6], o[7]);
        *(float4*)&dst[8]  = make_float4(o[8], o[9], o[10], o[11]);
        *(float4*)&dst[12] = make_float4(o[12], o[13], o[14], o[15]);
    }
}

// sums[batch[n]] += x1[n]; cnt[batch[n]] += 1 (sorted batch, boundary atomics)
__global__ void pool_kernel(const float* __restrict__ x1, const int* __restrict__ batch,
                            float* __restrict__ sums, float* __restrict__ cnt, int N) {
    constexpr int QG = 16, S = 16, ITER = 16;
    int t = threadIdx.x;
    int q = t % QG, s = t / QG;
    int n0 = blockIdx.x * (S * ITER) + s * ITER;
    float4 acc = make_float4(0.f, 0.f, 0.f, 0.f);
    float cacc = 0.f;
    int gcur = -1;
    for (int i = 0; i < ITER; ++i) {
        int n = n0 + i;
        if (n >= N) break;
        int gid = batch[n];
        if (gid != gcur) {
            if (gcur >= 0) {
                float* dst = &sums[gcur * 64 + q * 4];
                atomicAdd(dst + 0, acc.x);
                atomicAdd(dst + 1, acc.y);
                atomicAdd(dst + 2, acc.z);
                atomicAdd(dst + 3, acc.w);
                if (q == 0) atomicAdd(&cnt[gcur], cacc);
            }
            gcur = gid;
            acc = make_float4(0.f, 0.f, 0.f, 0.f);
            cacc = 0.f;
        }
        float4 a = ((const float4*)x1)[n * QG + q];
        acc.x += a.x; acc.y += a.y; acc.z += a.z; acc.w += a.w;
        if (q == 0) cacc += 1.f;
    }
    if (gcur >= 0) {
        float* dst = &sums[gcur * 64 + q * 4];
        atomicAdd(dst + 0, acc.x);
        atomicAdd(dst + 1, acc.y);
        atomicAdd(dst + 2, acc.z);
        atomicAdd(dst + 3, acc.w);
        if (q == 0) atomicAdd(&cnt[gcur], cacc);
    }
}

// Head: one block per graph. 128 threads: x2 (64) staged in LDS, thread k
// computes h[k] = relu(x2.fc1W[:,k] + b) (fc1W coalesced across threads),
// logits via per-wave shfl reduction (wave m -> logit m), log_softmax.
__global__ void head_kernel(const float* __restrict__ sums, const float* __restrict__ cnt,
                            const float* __restrict__ fc1W, const float* __restrict__ fc1b,
                            const float* __restrict__ fc2W, const float* __restrict__ fc2b,
                            float* __restrict__ out) {
    __shared__ float x2s[64];
    __shared__ float hs[128];
    __shared__ float lg[2];
    const int g = blockIdx.x;
    const int t = threadIdx.x;
    if (t < 64) {
        float c = fmaxf(cnt[g], 1.f);
        x2s[t] = sums[g * 64 + t] / c;
    }
    __syncthreads();
    {   // h[t] = relu(dot(x2, fc1W[:,t]) + fc1b[t]),  t = 0..127
        float a = fc1b[t];
        #pragma unroll 8
        for (int j = 0; j < 64; ++j) a += x2s[j] * fc1W[j * 128 + t];
        hs[t] = fmaxf(a, 0.f);
    }
    __syncthreads();
    {   // wave m (=t>>6) computes logit m by 64-lane reduction over 128 terms
        int m = t >> 6, l = t & 63;
        float p = hs[l] * fc2W[l * 2 + m] + hs[l + 64] * fc2W[(l + 64) * 2 + m];
        #pragma unroll
        for (int off = 1; off < 64; off <<= 1) p += __shfl_xor(p, off);
        if (l == 0) lg[m] = p + fc2b[m];
    }
    __syncthreads();
    if (t == 0) {
        float l0 = lg[0], l1 = lg[1];
        float mx = fmaxf(l0, l1);
        float lse = mx + logf(expf(l0 - mx) + expf(l1 - mx));
        out[g * 2 + 0] = l0 - lse;
        out[g * 2 + 1] = l1 - lse;
    }
}

extern "C" void kernel_launch(void* const* d_in, const int* in_sizes, int n_in,
                              void* d_out, int out_size, void* d_ws, size_t ws_size,
                              hipStream_t stream) {
    const float* x      = (const float*)d_in[0];
    const int*   eidx   = (const int*)d_in[1];
    const float* ew     = (const float*)d_in[2];
    const int*   batch  = (const int*)d_in[3];
    const float* W1     = (const float*)d_in[4];
    const float* b1     = (const float*)d_in[5];
    const float* W2     = (const float*)d_in[6];
    const float* b2     = (const float*)d_in[7];
    const float* fc1W   = (const float*)d_in[8];
    const float* fc1b   = (const float*)d_in[9];
    const float* fc2W   = (const float*)d_in[10];
    const float* fc2b   = (const float*)d_in[11];
    float* out = (float*)d_out;

    const int N = in_sizes[3];          // 50000 nodes
    const int E = in_sizes[2];          // 1600000 edges
    const int G = 64;
    const int* rows = eidx;
    const int* cols = eidx + E;
    const int NR = (N + 7) / 8;
    const int RSEG = E / 8 + 32768;

    float* ws = (float*)d_ws;
    size_t off = 0;
    auto alloc = [&](size_t n) { float* p = ws + off; off += (n + 15) & ~(size_t)15; return p; };
    // --- zero-initialized region ---
    float*    sums     = alloc(64 * 64);
    float*    cntf     = alloc(16);
    int*      ovfcnt   = (int*)alloc(16);
    int*      rangeCnt = (int*)alloc(16);
    int*      cnt      = (int*)alloc(N);          // zeroed for fallback path only
    size_t zfloats = off;
    // --- rest ---
    float*    dinv   = alloc(N);
    unsigned* slot   = (unsigned*)alloc((size_t)N * CAP);
    int4*     ovf    = (int4*)alloc((size_t)OVFCAP * 4);
    float*    bufA   = alloc((size_t)N * 128);   // h2d+w2d | xw1f8 | xw2f8 + x1
    float*    bufB   = alloc((size_t)N * 128);   // rng | h
    int*           h2d   = (int*)bufA;                        // 8*PCH*NR ints (6.4MB)
    int*           w2d   = h2d + (size_t)8 * PCH * NR;        // 8*PCH*NR ints (6.4MB)
    unsigned char* xw1f8 = (unsigned char*)bufA;              // [2][N][64] fp8 (6.4MB)
    unsigned char* xw2f8 = (unsigned char*)bufA;              // [1][N][64] fp8 (3.2MB)
    float*         x1    = bufA + (size_t)N * 32;             // [N][64] f32 at +6.4MB
    uint2*         rng   = (uint2*)bufB;                      // 8*RSEG uint2, dead before h
    float*         h     = bufB;
    (void)ws_size;

    hipMemsetAsync(d_ws, 0, zfloats * sizeof(float), stream);

    // CSR build: partition -> histogram(+wsum) -> prefix(+dinv) -> place
    if (NR <= MAXNR) {
        part_kernel<<<256, 256, 0, stream>>>(rows, cols, ew, rangeCnt, rng, E, NR, RSEG);
        hist2_kernel<<<8 * PCH, 1024, 0, stream>>>(rng, rangeCnt, h2d, w2d, NR, RSEG);
        scan2_kernel<<<(N + 255) / 256, 256, 0, stream>>>(h2d, w2d, cnt, dinv, NR, N);
        place2_kernel<<<8 * PCH, 1024, 0, stream>>>(rng, rangeCnt, h2d, slot, ovf, ovfcnt, NR, RSEG);
    } else {
        place_simple_kernel<<<(E + 255) / 256, 256, 0, stream>>>(rows, cols, ew, cnt, slot, ovf, ovfcnt, E);
        degfin_kernel<<<(N + 3) / 4, 256, 0, stream>>>(slot, cnt, ovf, ovfcnt, dinv, N);
    }

    // Layer 1: fp8 table, 2 slices of 64 features (3.2MB per XCD-group)
    gemm_kernel<128, 2><<<(N + 31) / 32, 256, 0, stream>>>(x, W1, dinv, xw1f8, N);
    gather_kernel<128, 2><<<((N + 15) / 16) * 2, 256, 0, stream>>>(xw1f8, slot, cnt, dinv, b1, ovf, ovfcnt, h, N);

    // Layer 2: fp8 table, 1 slice of 64 features (replicated read-only per XCD)
    gemm_kernel<64, 1><<<(N + 63) / 64, 256, 0, stream>>>(h, W2, dinv, xw2f8, N);
    gather_kernel<64, 1><<<(N + 15) / 16, 256, 0, stream>>>(xw2f8, slot, cnt, dinv, b2, ovf, ovfcnt, x1, N);

    // Mean-pool + head
    pool_kernel<<<(N + 255) / 256, 256, 0, stream>>>(x1, batch, sums, cntf, N);
    head_kernel<<<G, 128, 0, stream>>>(sums, cntf, fc1W, fc1b, fc2W, fc2b, out);
}

// Round 13
// 255.362 us; speedup vs baseline: 1.5555x; 1.0674x over previous
//
#include <hip/hip_runtime.h>
#include <hip/hip_bf16.h>

// ---------------------------------------------------------------------------
// GCN: h = relu(GCNConv(x,W1,b1)); x1 = relu(GCNConv(h,W2,b2));
//      x2 = meanpool(x1,batch); out = log_softmax(relu(x2@fc1+b)@fc2+b)
//
// R13: GEMMs moved to MFMA bf16 (fp32 VALU was the last compute-bound path):
// weights pre-transposed to bf16 [c][k] (stride 136, conflict-free b128),
// wave computes 16xBN tile via mfma_f32_16x16x32_bf16, epilogue packs fp8
// through padded LDS. h stored bf16 (halves h traffic, direct A-fragments
// for layer 2). Top-5 in R12 was only the harness's 268MB d_ws poison fill.
// ---------------------------------------------------------------------------

#define CAP 64
#define OVFCAP 8192
#define MAXNR 6400   // max nodes per range (LDS histogram)
#define PCH 32       // chunks per range in the place pipeline
#define BSTR 68      // LDS bucket stride (words)
#define KP 136       // bf16 weight row stride (128 + 8 pad)

typedef float v2f  __attribute__((ext_vector_type(2)));
typedef float f32x4 __attribute__((ext_vector_type(4)));
typedef short bf16x8 __attribute__((ext_vector_type(8)));

__device__ inline unsigned short f2bf(float f) {   // fp32 -> bf16 RNE
    unsigned u = __float_as_uint(f);
    u += 0x7FFFu + ((u >> 16) & 1u);
    return (unsigned short)(u >> 16);
}
__device__ inline void fp8x4_to_f32(unsigned w, float* o) {
    v2f lo = __builtin_amdgcn_cvt_pk_f32_fp8((int)w, false);
    v2f hi = __builtin_amdgcn_cvt_pk_f32_fp8((int)w, true);
    o[0] = lo[0]; o[1] = lo[1]; o[2] = hi[0]; o[3] = hi[1];
}
__device__ inline unsigned f32x4_to_fp8(float a, float b, float c, float d) {
    int w = 0;
    w = __builtin_amdgcn_cvt_pk_fp8_f32(a, b, w, false);
    w = __builtin_amdgcn_cvt_pk_fp8_f32(c, d, w, true);
    return (unsigned)w;
}

// Weight prep: wt[c][k] (bf16, stride KP) = W[k][c].  Block 0 -> W1, 1 -> W2.
__global__ void prepw_kernel(const float* __restrict__ W1, const float* __restrict__ W2,
                             unsigned short* __restrict__ wt1, unsigned short* __restrict__ wt2) {
    int t = threadIdx.x;
    if (blockIdx.x == 0) {
        for (int i = t; i < 128 * 128; i += 256) {
            int c = i >> 7, k = i & 127;
            wt1[c * KP + k] = f2bf(W1[k * 128 + c]);
        }
    } else {
        for (int i = t; i < 64 * 128; i += 256) {
            int c = i >> 7, k = i & 127;
            wt2[c * KP + k] = f2bf(W2[k * 64 + c]);
        }
    }
}

// P1: partition edges into 8 per-range lists rng[r] of (col, row<<15|q15(ew)).
__global__ void part_kernel(const int* __restrict__ rows, const int* __restrict__ cols,
                            const float* __restrict__ ew, int* __restrict__ rangeCnt,
                            uint2* __restrict__ rng, int E, int NR, int RSEG) {
    __shared__ int hc[8];
    const int t = threadIdx.x;
    const int nb = gridDim.x;
    const int CS = (E + nb - 1) / nb;
    const int e0 = blockIdx.x * CS, e1 = min(e0 + CS, E);
    if (t < 8) hc[t] = 0;
    __syncthreads();
    for (int e = e0 + t; e < e1; e += 256) {
        int r = cols[e] / NR;
        atomicAdd(&hc[r], 1);
    }
    __syncthreads();
    if (t < 8) hc[t] = atomicAdd(&rangeCnt[t], hc[t]);   // hc becomes cursor base
    __syncthreads();
    for (int e = e0 + t; e < e1; e += 256) {
        int c = cols[e];
        int r = c / NR;
        int q = (int)(ew[e] * 32768.0f);
        if (q > 32767) q = 32767;
        unsigned rec = ((unsigned)rows[e] << 15) | (unsigned)q;
        int pos = atomicAdd(&hc[r], 1);
        if (pos < RSEG) rng[(size_t)r * RSEG + pos] = make_uint2((unsigned)c, rec);
    }
}

// P2a: per-(range,chunk) LDS histogram + q15 weight sum
__global__ __launch_bounds__(1024)
void hist2_kernel(const uint2* __restrict__ rng, const int* __restrict__ rangeCnt,
                  int* __restrict__ h2d, int* __restrict__ w2d, int NR, int RSEG) {
    __shared__ int hist[MAXNR];
    __shared__ int wsum[MAXNR];
    const int r = blockIdx.x & 7, j = blockIdx.x >> 3;
    const int t = threadIdx.x;
    const int M = min(rangeCnt[r], RSEG);
    const int CS = (M + PCH - 1) / PCH;
    const int e0 = j * CS, e1 = min(e0 + CS, M);
    for (int n = t; n < NR; n += 1024) { hist[n] = 0; wsum[n] = 0; }
    __syncthreads();
    const uint2* lst = rng + (size_t)r * RSEG;
    for (int k = e0 + t; k < e1; k += 1024) {
        unsigned c = lst[k].x - r * NR;
        atomicAdd(&hist[c], 1);
        atomicAdd(&wsum[c], (int)(lst[k].y & 32767u));
    }
    __syncthreads();
    int* dst = h2d + (size_t)(r * PCH + j) * NR;
    int* wdst = w2d + (size_t)(r * PCH + j) * NR;
    for (int n = t; n < NR; n += 1024) { dst[n] = hist[n]; wdst[n] = wsum[n]; }
}

// P2b: per-node exclusive prefix -> bases in h2d, total -> cnt, dinv from wsum.
__global__ void scan2_kernel(int* __restrict__ h2d, const int* __restrict__ w2d,
                             int* __restrict__ cnt, float* __restrict__ dinv, int NR, int N) {
    int n = blockIdx.x * 256 + threadIdx.x;
    if (n >= N) return;
    int r = n / NR, c = n - r * NR;
    int* col = h2d + (size_t)(r * PCH) * NR + c;
    const int* wcol = w2d + (size_t)(r * PCH) * NR + c;
    int run = 0;
    long long ws = 0;
    #pragma unroll 8
    for (int j = 0; j < PCH; ++j) {
        int v = col[(size_t)j * NR];
        col[(size_t)j * NR] = run;
        run += v;
        ws += wcol[(size_t)j * NR];
    }
    cnt[n] = run;
    dinv[n] = rsqrtf((float)ws * (1.0f / 32768.0f) + 1.0f);
}

// P2c: write slot records at deterministic positions (chunk base + LDS cursor).
__global__ __launch_bounds__(1024)
void place2_kernel(const uint2* __restrict__ rng, const int* __restrict__ rangeCnt,
                   const int* __restrict__ h2d, unsigned* __restrict__ slot,
                   int4* __restrict__ ovf, int* __restrict__ ovfcnt,
                   int NR, int RSEG) {
    __shared__ int cur[MAXNR];
    const int r = blockIdx.x & 7, j = blockIdx.x >> 3;
    const int t = threadIdx.x;
    const int M = min(rangeCnt[r], RSEG);
    const int CS = (M + PCH - 1) / PCH;
    const int e0 = j * CS, e1 = min(e0 + CS, M);
    const int* src = h2d + (size_t)(r * PCH + j) * NR;
    for (int n = t; n < NR; n += 1024) cur[n] = src[n];
    __syncthreads();
    const uint2* lst = rng + (size_t)r * RSEG;
    for (int k = e0 + t; k < e1; k += 1024) {
        uint2 u2 = lst[k];
        int pos = atomicAdd(&cur[u2.x - r * NR], 1);   // LDS cursor
        if (pos < CAP) {
            slot[(size_t)u2.x * CAP + pos] = u2.y;
        } else {
            int o = atomicAdd(ovfcnt, 1);
            if (o < OVFCAP)
                ovf[o] = make_int4((int)(u2.y >> 15), (int)u2.x, (int)(u2.y & 32767u), 0);
        }
    }
}

// Fallback for N too large for LDS histogram (not taken here).
__global__ void place_simple_kernel(const int* __restrict__ rows, const int* __restrict__ cols,
                                    const float* __restrict__ ew, int* __restrict__ cnt,
                                    unsigned* __restrict__ slot, int4* __restrict__ ovf,
                                    int* __restrict__ ovfcnt, int E) {
    int e = blockIdx.x * 256 + threadIdx.x;
    if (e >= E) return;
    int r = rows[e], c = cols[e];
    int q = (int)(ew[e] * 32768.0f);
    if (q > 32767) q = 32767;
    int pos = atomicAdd(&cnt[c], 1);
    if (pos < CAP) {
        slot[(size_t)c * CAP + pos] = ((unsigned)r << 15) | (unsigned)q;
    } else {
        int o = atomicAdd(ovfcnt, 1);
        if (o < OVFCAP) ovf[o] = make_int4(r, c, q, 0);
    }
}

// Fallback-path dinv (normal path computes dinv in scan2).
__global__ void degfin_kernel(const unsigned* __restrict__ slot, const int* __restrict__ cnt,
                              const int4* __restrict__ ovf, const int* __restrict__ ovfcnt,
                              float* __restrict__ dinv, int N) {
    const int w = threadIdx.x >> 6, lane = threadIdx.x & 63;
    const int i = blockIdx.x * 4 + w;
    if (i >= N) return;
    int mraw = cnt[i];
    int m = mraw > CAP ? CAP : mraw;
    float v = 0.f;
    if (lane < m) v = (float)(slot[(size_t)i * CAP + lane] & 32767u);
    if (mraw > CAP) {
        int oc = *ovfcnt; if (oc > OVFCAP) oc = OVFCAP;
        for (int k = lane; k < oc; k += 64)
            if (ovf[k].y == i) v += (float)ovf[k].z;
    }
    #pragma unroll
    for (int off = 1; off < 64; off <<= 1) v += __shfl_xor(v, off);
    if (lane == 0) dinv[i] = rsqrtf(v * (1.0f / 32768.0f) + 1.0f);
}

// MFMA bf16 GEMM -> fp8 sliced table. outf8[slice][M][64] = (A@W)*dinv[row].
// A: [M][128] (fp32 if AF32 else bf16). wt: [BN][KP] bf16 = W^T.
// Block: 256 thr = 4 waves; wave w -> rows blockIdx*64 + w*16 .. +16.
// Fragments (m89-verified): A[m=lane&15][k=quad*8+j]; B[k=quad*8+j][n=lane&15];
// D col=lane&15, row=quad*4+reg. Epilogue transposes via padded LDS, packs fp8.
template <int BN, bool AF32>
__global__ __launch_bounds__(256)
void gemm_mfma_kernel(const void* __restrict__ Av, const unsigned short* __restrict__ wt,
                      const float* __restrict__ dinv, unsigned char* __restrict__ outf8,
                      int M) {
    constexpr int CT = BN / 16;          // col tiles
    constexpr int EPS = BN + 4;          // epilogue LDS row stride (floats)
    __shared__ unsigned short wl[BN * KP];
    __shared__ float ep[4][16 * EPS];
    const int t = threadIdx.x;
    for (int i = t; i < BN * KP / 8; i += 256)
        ((uint4*)wl)[i] = ((const uint4*)wt)[i];
    __syncthreads();
    const int w = t >> 6, lane = t & 63;
    const int n16 = lane & 15, q = lane >> 4;
    const int rowBase = blockIdx.x * 64 + w * 16;
    int arow = rowBase + n16; if (arow >= M) arow = M - 1;
    f32x4 acc[CT];
    #pragma unroll
    for (int ct = 0; ct < CT; ++ct) acc[ct] = (f32x4){0.f, 0.f, 0.f, 0.f};
    #pragma unroll
    for (int kt = 0; kt < 4; ++kt) {
        bf16x8 af;
        if (AF32) {
            const float* ap = (const float*)Av + (size_t)arow * 128 + kt * 32 + q * 8;
            float4 a0 = *(const float4*)ap;
            float4 a1 = *(const float4*)(ap + 4);
            af[0] = (short)f2bf(a0.x); af[1] = (short)f2bf(a0.y);
            af[2] = (short)f2bf(a0.z); af[3] = (short)f2bf(a0.w);
            af[4] = (short)f2bf(a1.x); af[5] = (short)f2bf(a1.y);
            af[6] = (short)f2bf(a1.z); af[7] = (short)f2bf(a1.w);
        } else {
            af = *(const bf16x8*)((const unsigned short*)Av + (size_t)arow * 128 + kt * 32 + q * 8);
        }
        #pragma unroll
        for (int ct = 0; ct < CT; ++ct) {
            bf16x8 bfr = *(const bf16x8*)&wl[(ct * 16 + n16) * KP + kt * 32 + q * 8];
            acc[ct] = __builtin_amdgcn_mfma_f32_16x16x32_bf16(af, bfr, acc[ct], 0, 0, 0);
        }
    }
    // dump D tiles: lane holds D[row=q*4+r][col=ct*16+n16]
    #pragma unroll
    for (int ct = 0; ct < CT; ++ct)
        #pragma unroll
        for (int r = 0; r < 4; ++r)
            ep[w][(q * 4 + r) * EPS + ct * 16 + n16] = acc[ct][r];
    __syncthreads();
    // pack: lane -> row (lane&15), col chunk (lane>>4)*(BN/4); 16 fp8 per uint4
    const int lr = lane & 15;
    const int cc = (lane >> 4) * (BN / 4);
    int grow = rowBase + lr;
    if (grow < M) {
        float s = dinv[grow];
        const float* src = &ep[w][lr * EPS + cc];
        #pragma unroll
        for (int u = 0; u < BN / 64; ++u) {
            int col0 = cc + u * 16;
            int slice = col0 >> 6, cw = col0 & 63;
            unsigned w0 = f32x4_to_fp8(src[u*16+ 0]*s, src[u*16+ 1]*s, src[u*16+ 2]*s, src[u*16+ 3]*s);
            unsigned w1 = f32x4_to_fp8(src[u*16+ 4]*s, src[u*16+ 5]*s, src[u*16+ 6]*s, src[u*16+ 7]*s);
            unsigned w2 = f32x4_to_fp8(src[u*16+ 8]*s, src[u*16+ 9]*s, src[u*16+10]*s, src[u*16+11]*s);
            unsigned w3 = f32x4_to_fp8(src[u*16+12]*s, src[u*16+13]*s, src[u*16+14]*s, src[u*16+15]*s);
            *(uint4*)&outf8[((size_t)slice * M + grow) * 64 + cw] = make_uint4(w0, w1, w2, w3);
        }
    }
}

// Sliced fp8 aggregation with LDS-staged buckets (see R10/R11 notes).
// OB: output bf16 (layer1 h) vs fp32 (layer2 x1).
template <int F, int S, bool OB>
__global__ void gather_kernel(const unsigned char* __restrict__ xsb,
                              const unsigned* __restrict__ slot,
                              const int* __restrict__ cnt, const float* __restrict__ dinv,
                              const float* __restrict__ b, const int4* __restrict__ ovf,
                              const int* __restrict__ ovfcnt, void* __restrict__ outv, int N) {
    constexpr int EPN = 4;           // edges in flight per node
    __shared__ unsigned sbkt[16 * BSTR];
    const int slice = (S > 1) ? ((int)blockIdx.x % S) : 0;
    const int grp = (S > 1) ? ((int)blockIdx.x / S) : blockIdx.x;
    const int t = threadIdx.x;
    const int node0 = grp * 16;
    {   // stage 16 buckets (coalesced): thread t -> bucket t/16, chunk t%16
        int ndl = t >> 4, part = t & 15;
        int snode = node0 + ndl; if (snode >= N) snode = N - 1;
        *(uint4*)&sbkt[ndl * BSTR + part * 4] =
            *(const uint4*)&slot[(size_t)snode * CAP + part * 4];
    }
    __syncthreads();
    const int w = t >> 6, lane = t & 63;
    const int cg = lane & 3;
    const int e  = (lane >> 2) & 3;
    const int nd = lane >> 4;
    const int ndl = w * 4 + nd;          // local node 0..15
    const int i = node0 + ndl;
    const bool iv = (i < N);
    const int ic = iv ? i : 0;
    const uint4* xs4 = (const uint4*)(xsb + (size_t)slice * N * 64);
    int mraw = iv ? cnt[ic] : 0;
    int m = mraw > CAP ? CAP : mraw;
    const unsigned* lb = &sbkt[ndl * BSTR];
    float acc[16] = {};
    int j = e;
    for (; j + EPN < m; j += 2 * EPN) {
        unsigned u0 = lb[j], u1 = lb[j + EPN];
        float c0 = (float)(u0 & 32767u), c1 = (float)(u1 & 32767u);
        uint4 a0 = xs4[(size_t)(u0 >> 15) * 4 + cg];
        uint4 a1 = xs4[(size_t)(u1 >> 15) * 4 + cg];
        float f0[16], f1[16];
        fp8x4_to_f32(a0.x, f0 + 0);  fp8x4_to_f32(a0.y, f0 + 4);
        fp8x4_to_f32(a0.z, f0 + 8);  fp8x4_to_f32(a0.w, f0 + 12);
        fp8x4_to_f32(a1.x, f1 + 0);  fp8x4_to_f32(a1.y, f1 + 4);
        fp8x4_to_f32(a1.z, f1 + 8);  fp8x4_to_f32(a1.w, f1 + 12);
        #pragma unroll
        for (int k = 0; k < 16; ++k) acc[k] += f0[k] * c0 + f1[k] * c1;
    }
    if (j < m) {
        unsigned u = lb[j];
        float c = (float)(u & 32767u);
        uint4 a = xs4[(size_t)(u >> 15) * 4 + cg];
        float f[16];
        fp8x4_to_f32(a.x, f + 0);  fp8x4_to_f32(a.y, f + 4);
        fp8x4_to_f32(a.z, f + 8);  fp8x4_to_f32(a.w, f + 12);
        #pragma unroll
        for (int k = 0; k < 16; ++k) acc[k] += f[k] * c;
    }
    if (mraw > CAP) {                     // inline overflow (normally skipped)
        int oc = *ovfcnt; if (oc > OVFCAP) oc = OVFCAP;
        for (int k = e; k < oc; k += EPN) {
            int4 r4 = ovf[k];
            if (r4.y == i) {
                float c = (float)r4.z;
                uint4 a = xs4[(size_t)r4.x * 4 + cg];
                float f[16];
                fp8x4_to_f32(a.x, f + 0);  fp8x4_to_f32(a.y, f + 4);
                fp8x4_to_f32(a.z, f + 8);  fp8x4_to_f32(a.w, f + 12);
                #pragma unroll
                for (int kk = 0; kk < 16; ++kk) acc[kk] += f[kk] * c;
            }
        }
    }
    #pragma unroll
    for (int k = 0; k < 16; ++k) {
        acc[k] += __shfl_xor(acc[k], 4);
        acc[k] += __shfl_xor(acc[k], 8);
    }
    if (e == 0 && iv) {
        float d = dinv[i];
        float sa = d * (1.0f / 32768.0f);
        uint4 sv = xs4[(size_t)i * 4 + cg];
        float sf[16];
        fp8x4_to_f32(sv.x, sf + 0);  fp8x4_to_f32(sv.y, sf + 4);
        fp8x4_to_f32(sv.z, sf + 8);  fp8x4_to_f32(sv.w, sf + 12);
        const float* bb = &b[slice * 64 + cg * 16];
        float o[16];
        #pragma unroll
        for (int k = 0; k < 16; ++k)
            o[k] = fmaxf(acc[k] * sa + sf[k] * d + bb[k], 0.f);
        if (OB) {
            unsigned short* dst = (unsigned short*)outv + (size_t)i * F + slice * 64 + cg * 16;
            unsigned pw[8];
            #pragma unroll
            for (int k = 0; k < 8; ++k)
                pw[k] = (unsigned)f2bf(o[2 * k]) | ((unsigned)f2bf(o[2 * k + 1]) << 16);
            *(uint4*)&dst[0] = make_uint4(pw[0], pw[1], pw[2], pw[3]);
            *(uint4*)&dst[8] = make_uint4(pw[4], pw[5], pw[6], pw[7]);
        } else {
            float* dst = (float*)outv + (size_t)i * F + slice * 64 + cg * 16;
            *(float4*)&dst[0]  = make_float4(o[0], o[1], o[2], o[3]);
            *(float4*)&dst[4]  = make_float4(o[4], o[5], o[6], o[7]);
            *(float4*)&dst[8]  = make_float4(o[8], o[9], o[10], o[11]);
            *(float4*)&dst[12] = make_float4(o[12], o[13], o[14], o[15]);
        }
    }
}

// sums[batch[n]] += x1[n]; cnt[batch[n]] += 1 (sorted batch, boundary atomics)
__global__ void pool_kernel(const float* __restrict__ x1, const int* __restrict__ batch,
                            float* __restrict__ sums, float* __restrict__ cnt, int N) {
    constexpr int QG = 16, S = 16, ITER = 16;
    int t = threadIdx.x;
    int q = t % QG, s = t / QG;
    int n0 = blockIdx.x * (S * ITER) + s * ITER;
    float4 acc = make_float4(0.f, 0.f, 0.f, 0.f);
    float cacc = 0.f;
    int gcur = -1;
    for (int i = 0; i < ITER; ++i) {
        int n = n0 + i;
        if (n >= N) break;
        int gid = batch[n];
        if (gid != gcur) {
            if (gcur >= 0) {
                float* dst = &sums[gcur * 64 + q * 4];
                atomicAdd(dst + 0, acc.x);
                atomicAdd(dst + 1, acc.y);
                atomicAdd(dst + 2, acc.z);
                atomicAdd(dst + 3, acc.w);
                if (q == 0) atomicAdd(&cnt[gcur], cacc);
            }
            gcur = gid;
            acc = make_float4(0.f, 0.f, 0.f, 0.f);
            cacc = 0.f;
        }
        float4 a = ((const float4*)x1)[n * QG + q];
        acc.x += a.x; acc.y += a.y; acc.z += a.z; acc.w += a.w;
        if (q == 0) cacc += 1.f;
    }
    if (gcur >= 0) {
        float* dst = &sums[gcur * 64 + q * 4];
        atomicAdd(dst + 0, acc.x);
        atomicAdd(dst + 1, acc.y);
        atomicAdd(dst + 2, acc.z);
        atomicAdd(dst + 3, acc.w);
        if (q == 0) atomicAdd(&cnt[gcur], cacc);
    }
}

// Head: one block per graph (see R12 notes).
__global__ void head_kernel(const float* __restrict__ sums, const float* __restrict__ cnt,
                            const float* __restrict__ fc1W, const float* __restrict__ fc1b,
                            const float* __restrict__ fc2W, const float* __restrict__ fc2b,
                            float* __restrict__ out) {
    __shared__ float x2s[64];
    __shared__ float hs[128];
    __shared__ float lg[2];
    const int g = blockIdx.x;
    const int t = threadIdx.x;
    if (t < 64) {
        float c = fmaxf(cnt[g], 1.f);
        x2s[t] = sums[g * 64 + t] / c;
    }
    __syncthreads();
    {
        float a = fc1b[t];
        #pragma unroll 8
        for (int j = 0; j < 64; ++j) a += x2s[j] * fc1W[j * 128 + t];
        hs[t] = fmaxf(a, 0.f);
    }
    __syncthreads();
    {
        int m = t >> 6, l = t & 63;
        float p = hs[l] * fc2W[l * 2 + m] + hs[l + 64] * fc2W[(l + 64) * 2 + m];
        #pragma unroll
        for (int off = 1; off < 64; off <<= 1) p += __shfl_xor(p, off);
        if (l == 0) lg[m] = p + fc2b[m];
    }
    __syncthreads();
    if (t == 0) {
        float l0 = lg[0], l1 = lg[1];
        float mx = fmaxf(l0, l1);
        float lse = mx + logf(expf(l0 - mx) + expf(l1 - mx));
        out[g * 2 + 0] = l0 - lse;
        out[g * 2 + 1] = l1 - lse;
    }
}

extern "C" void kernel_launch(void* const* d_in, const int* in_sizes, int n_in,
                              void* d_out, int out_size, void* d_ws, size_t ws_size,
                              hipStream_t stream) {
    const float* x      = (const float*)d_in[0];
    const int*   eidx   = (const int*)d_in[1];
    const float* ew     = (const float*)d_in[2];
    const int*   batch  = (const int*)d_in[3];
    const float* W1     = (const float*)d_in[4];
    const float* b1     = (const float*)d_in[5];
    const float* W2     = (const float*)d_in[6];
    const float* b2     = (const float*)d_in[7];
    const float* fc1W   = (const float*)d_in[8];
    const float* fc1b   = (const float*)d_in[9];
    const float* fc2W   = (const float*)d_in[10];
    const float* fc2b   = (const float*)d_in[11];
    float* out = (float*)d_out;

    const int N = in_sizes[3];          // 50000 nodes
    const int E = in_sizes[2];          // 1600000 edges
    const int G = 64;
    const int* rows = eidx;
    const int* cols = eidx + E;
    const int NR = (N + 7) / 8;
    const int RSEG = E / 8 + 32768;

    float* ws = (float*)d_ws;
    size_t off = 0;
    auto alloc = [&](size_t n) { float* p = ws + off; off += (n + 15) & ~(size_t)15; return p; };
    // --- zero-initialized region ---
    float*    sums     = alloc(64 * 64);
    float*    cntf     = alloc(16);
    int*      ovfcnt   = (int*)alloc(16);
    int*      rangeCnt = (int*)alloc(16);
    int*      cnt      = (int*)alloc(N);          // zeroed for fallback path only
    size_t zfloats = off;
    // --- rest ---
    float*    dinv   = alloc(N);
    unsigned short* wt1 = (unsigned short*)alloc(128 * KP / 2 + 16);
    unsigned short* wt2 = (unsigned short*)alloc(64 * KP / 2 + 16);
    unsigned* slot   = (unsigned*)alloc((size_t)N * CAP);
    int4*     ovf    = (int4*)alloc((size_t)OVFCAP * 4);
    float*    bufA   = alloc((size_t)N * 128);   // h2d+w2d | xw1f8 | xw2f8 + x1
    float*    bufB   = alloc((size_t)N * 128);   // rng | h(bf16)
    int*            h2d   = (int*)bufA;                        // 8*PCH*NR ints
    int*            w2d   = h2d + (size_t)8 * PCH * NR;        // 8*PCH*NR ints
    unsigned char*  xw1f8 = (unsigned char*)bufA;              // [2][N][64] fp8
    unsigned char*  xw2f8 = (unsigned char*)bufA;              // [1][N][64] fp8
    float*          x1    = bufA + (size_t)N * 32;             // [N][64] f32 at +6.4MB
    uint2*          rng   = (uint2*)bufB;                      // 8*RSEG uint2, dead before h
    unsigned short* hbf   = (unsigned short*)bufB;             // [N][128] bf16
    (void)ws_size;

    hipMemsetAsync(d_ws, 0, zfloats * sizeof(float), stream);

    // Weight prep (independent of CSR build)
    prepw_kernel<<<2, 256, 0, stream>>>(W1, W2, wt1, wt2);

    // CSR build: partition -> histogram(+wsum) -> prefix(+dinv) -> place
    if (NR <= MAXNR) {
        part_kernel<<<256, 256, 0, stream>>>(rows, cols, ew, rangeCnt, rng, E, NR, RSEG);
        hist2_kernel<<<8 * PCH, 1024, 0, stream>>>(rng, rangeCnt, h2d, w2d, NR, RSEG);
        scan2_kernel<<<(N + 255) / 256, 256, 0, stream>>>(h2d, w2d, cnt, dinv, NR, N);
        place2_kernel<<<8 * PCH, 1024, 0, stream>>>(rng, rangeCnt, h2d, slot, ovf, ovfcnt, NR, RSEG);
    } else {
        place_simple_kernel<<<(E + 255) / 256, 256, 0, stream>>>(rows, cols, ew, cnt, slot, ovf, ovfcnt, E);
        degfin_kernel<<<(N + 3) / 4, 256, 0, stream>>>(slot, cnt, ovf, ovfcnt, dinv, N);
    }

    // Layer 1: MFMA gemm (fp32 A) -> fp8 table (2 slices); gather -> h (bf16)
    gemm_mfma_kernel<128, true><<<(N + 63) / 64, 256, 0, stream>>>(x, wt1, dinv, xw1f8, N);
    gather_kernel<128, 2, true><<<((N + 15) / 16) * 2, 256, 0, stream>>>(xw1f8, slot, cnt, dinv, b1, ovf, ovfcnt, hbf, N);

    // Layer 2: MFMA gemm (bf16 A = h) -> fp8 table (1 slice); gather -> x1 (f32)
    gemm_mfma_kernel<64, false><<<(N + 63) / 64, 256, 0, stream>>>(hbf, wt2, dinv, xw2f8, N);
    gather_kernel<64, 1, false><<<(N + 15) / 16, 256, 0, stream>>>(xw2f8, slot, cnt, dinv, b2, ovf, ovfcnt, x1, N);

    // Mean-pool + head
    pool_kernel<<<(N + 255) / 256, 256, 0, stream>>>(x1, batch, sums, cntf, N);
    head_kernel<<<G, 128, 0, stream>>>(sums, cntf, fc1W, fc1b, fc2W, fc2b, out);
}